// Round 11
// baseline (1487.517 us; speedup 1.0000x reference)
//
#include <hip/hip_runtime.h>
#include <math.h>

#define DEVI static __device__ __forceinline__
#define F_INF __builtin_inff()

typedef short bf16x8 __attribute__((ext_vector_type(8)));    // 8 bf16 = 4 VGPR
typedef float floatx4 __attribute__((ext_vector_type(4)));   // MFMA acc
typedef unsigned short ub16x4 __attribute__((ext_vector_type(4)));

// bf16 round-to-nearest-even helpers (finite data only)
DEVI unsigned short bf16rne(float f)
{
    unsigned u = __float_as_uint(f);
    unsigned r = (u + 0x7FFFu + ((u >> 16) & 1u)) >> 16;
    return (unsigned short)r;
}
DEVI float bf16tof(unsigned short h) { return __uint_as_float(((unsigned)h) << 16); }

// ---------------------------------------------------------------------------
// Exactness scheme for kNN top-20 (set semantics — idx feeds max-pools only):
//  * each of 8 lists per query scans a disjoint candidate range in ASCENDING
//    index order, sorted top-20 with plain strict-< insertion,
//  * k_merge8 does a full (d, idx)-lexicographic tournament over the 8 lists
//    -> global top-20 set == jax.lax.top_k's set (list order irrelevant).
// bf16x3 split-MFMA dot (hh+hm+mh+mm+hl+lh): error ~2^-24 relative — verified
// absmax 0.0 end-to-end in v7-v11.
DEVI bool lexlt(float d, int i, float dr, int ir)
{
    return (d < dr) || (d == dr && i < ir);
}

// plain-< sorted insertion; (INF, any) is a guaranteed no-op.
DEVI void insert20(float* bd, int* bi, float d, int i)
{
#pragma unroll
    for (int j = 19; j >= 1; --j) {
        bool lt  = d < bd[j];
        bool ltp = d < bd[j - 1];
        float nd = ltp ? bd[j - 1] : d;
        int   ni = ltp ? bi[j - 1] : i;
        bd[j] = lt ? nd : bd[j];
        bi[j] = lt ? ni : bi[j];
    }
    bool lt0 = d < bd[0];
    bd[0] = lt0 ? d : bd[0];
    bi[0] = lt0 ? i : bi[0];
}

DEVI void insert_tiered(float* bd, int* bi, float d, int i)
{
    if (__all(!(d < bd[15]))) {
#pragma unroll
        for (int j = 19; j >= 17; --j) {
            bool lt  = d < bd[j];
            bool ltp = d < bd[j - 1];
            float nd = ltp ? bd[j - 1] : d;
            int   ni = ltp ? bi[j - 1] : i;
            bd[j] = lt ? nd : bd[j];
            bi[j] = lt ? ni : bi[j];
        }
        bool lt16 = d < bd[16];
        bd[16] = lt16 ? d : bd[16];
        bi[16] = lt16 ? i : bi[16];
    } else if (__all(!(d < bd[7]))) {
#pragma unroll
        for (int j = 19; j >= 9; --j) {
            bool lt  = d < bd[j];
            bool ltp = d < bd[j - 1];
            float nd = ltp ? bd[j - 1] : d;
            int   ni = ltp ? bi[j - 1] : i;
            bd[j] = lt ? nd : bd[j];
            bi[j] = lt ? ni : bi[j];
        }
        bool lt8 = d < bd[8];
        bd[8] = lt8 ? d : bd[8];
        bi[8] = lt8 ? i : bi[8];
    } else {
        insert20(bd, bi, d, i);
    }
}

DEVI void flushT(float* bd, int* bi, float d, int i, int e, int cnt)
{
    bool want = (e < cnt) && (d < bd[19]);
    if (__any(want))
        insert_tiered(bd, bi, want ? d : F_INF, want ? i : 0x7FFFFFFF);
}

// register append-buffer (cap 4) + wave-coupled flush
#define FLUSH() do { \
    flushT(bd, bi, a0, j0, 0, cnt); \
    flushT(bd, bi, a1, j1, 1, cnt); \
    flushT(bd, bi, a2, j2, 2, cnt); \
    flushT(bd, bi, a3, j3, 3, cnt); \
    cnt = 0; thr = bd[19]; \
} while (0)

#define APPEND(dv, civ) do { \
    bool pass_ = (dv) < thr; \
    if (pass_) { \
        a0 = (cnt == 0) ? (dv) : a0; j0 = (cnt == 0) ? (civ) : j0; \
        a1 = (cnt == 1) ? (dv) : a1; j1 = (cnt == 1) ? (civ) : j1; \
        a2 = (cnt == 2) ? (dv) : a2; j2 = (cnt == 2) ? (civ) : j2; \
        a3 = (cnt == 3) ? (dv) : a3; j3 = (cnt == 3) ? (civ) : j3; \
        ++cnt; \
    } \
    if (__any(cnt == 4)) { FLUSH(); } \
} while (0)

// ---------------------------------------------------------------------------
// K-merge: exact 8-way lex tournament. LIST-MAJOR layout —
// partD/partI[(list*32768 + q)*20 + p], list stride LS = 655360.
__global__ __launch_bounds__(64) void k_merge8(const float* __restrict__ partD,
                                               const int* __restrict__ partI,
                                               int* __restrict__ idxo)
{
    const size_t LS = 655360;           // 32768 * 20
    int q = blockIdx.x * 64 + threadIdx.x;
    const float* rd = partD + (size_t)q * 20;
    const int*   ri = partI + (size_t)q * 20;
    int p0 = 0, p1 = 0, p2 = 0, p3 = 0, p4 = 0, p5 = 0, p6 = 0, p7 = 0;
    int* op = idxo + (size_t)q * 20;
    for (int r = 0; r < 20; ++r) {      // p <= r < 20 at read time: never OOB
        float d0 = rd[p0],            d1 = rd[LS + p1];
        float d2v = rd[2 * LS + p2],  d3 = rd[3 * LS + p3];
        float d4 = rd[4 * LS + p4],   d5 = rd[5 * LS + p5];
        float d6 = rd[6 * LS + p6],   d7 = rd[7 * LS + p7];
        int   i0 = ri[p0],            i1 = ri[LS + p1];
        int   i2 = ri[2 * LS + p2],   i3 = ri[3 * LS + p3];
        int   i4v = ri[4 * LS + p4],  i5 = ri[5 * LS + p5];
        int   i6 = ri[6 * LS + p6],   i7 = ri[7 * LS + p7];
        bool wA = lexlt(d1, i1, d0, i0);   float dA = wA ? d1 : d0; int iA = wA ? i1 : i0; int sA = wA ? 1 : 0;
        bool wB = lexlt(d3, i3, d2v, i2);  float dB = wB ? d3 : d2v; int iB = wB ? i3 : i2; int sB = wB ? 3 : 2;
        bool wC = lexlt(d5, i5, d4, i4v);  float dC = wC ? d5 : d4; int iC = wC ? i5 : i4v; int sC = wC ? 5 : 4;
        bool wD = lexlt(d7, i7, d6, i6);   float dD = wD ? d7 : d6; int iD = wD ? i7 : i6; int sD = wD ? 7 : 6;
        bool wE = lexlt(dB, iB, dA, iA);   float dE = wE ? dB : dA; int iE = wE ? iB : iA; int sE = wE ? sB : sA;
        bool wF = lexlt(dD, iD, dC, iC);   float dF = wF ? dD : dC; int iF = wF ? iD : iC; int sF = wF ? sD : sC;
        bool wG = lexlt(dF, iF, dE, iE);   int ig = wG ? iF : iE;   int sg = wG ? sF : sE;
        op[r] = ig;
        p0 += (sg == 0); p1 += (sg == 1); p2 += (sg == 2); p3 += (sg == 3);
        p4 += (sg == 4); p5 += (sg == 5); p6 += (sg == 6); p7 += (sg == 7);
    }
}

// ---------------------------------------------------------------------------
// K1: exact kNN on 2D points. 1024 blocks = 8 b x 64 qtile x 2 split.
// list-major part writes.
__global__ __launch_bounds__(256, 4) void k_knn2d(const float* __restrict__ x,
                                                  float* __restrict__ partD, int* __restrict__ partI)
{
    __shared__ float2 pts[4096];
    int t = threadIdx.x;
    int blk = blockIdx.x;
    int b = blk >> 7;
    int qt = (blk >> 1) & 63;
    int s = blk & 1;
    const float* xb = x + (size_t)b * 4096 * 2;
    for (int f = t; f < 2048; f += 256)
        ((float4*)pts)[f] = ((const float4*)xb)[f];
    __syncthreads();

    int l = t & 63, w = t >> 6;
    int q = qt * 64 + l;
    float2 qp = pts[q];
    float d2i = qp.x * qp.x + qp.y * qp.y;

    float bd[20]; int bi[20];
#pragma unroll
    for (int j = 0; j < 20; ++j) { bd[j] = F_INF; bi[j] = -1; }
    int cnt = 0; float thr = F_INF;
    float a0 = 0, a1 = 0, a2 = 0, a3 = 0;
    int   j0 = 0, j1 = 0, j2 = 0, j3 = 0;

    int m0 = s * 2048 + w * 512;
    for (int m = m0; m < m0 + 512; ++m) {
        float2 p = pts[m];                       // wave-uniform -> broadcast
        float d2j = p.x * p.x + p.y * p.y;
        float dot = qp.x * p.x + qp.y * p.y;
        float dist = (d2i + d2j) - 2.0f * dot;
        APPEND(dist, m);
    }
    FLUSH();

    size_t base = (((size_t)(s * 4 + w)) * 32768 + (b * 4096 + q)) * 20;
#pragma unroll
    for (int k = 0; k < 20; ++k) { partD[base + k] = bd[k]; partI[base + k] = bi[k]; }
}

// ---------------------------------------------------------------------------
// K2a: per-point layer-1 decomposition.
__global__ void k_prep1(const float* __restrict__ x, const float* __restrict__ w1,
                        const float* __restrict__ b1, float* __restrict__ pm, float* __restrict__ qv)
{
    int tid = blockIdx.x * 256 + threadIdx.x;   // 8*4096*64
    int n = tid >> 6, i = tid & 63;
    float x0 = x[(size_t)n * 2], x1v = x[(size_t)n * 2 + 1];
    float wa = w1[i], wb = w1[64 + i], wc = w1[128 + i], wd = w1[192 + i];
    pm[tid] = fmaf(x0, wa - wc, fmaf(x1v, wb - wd, b1[i]));
    qv[tid] = fmaf(x0, wc, x1v * wd);
}

// ---------------------------------------------------------------------------
// K2: EdgeConv-1 main. 20-lane groups, segmented shuffle max.
// v12: bf16x3 split FUSED into the k==0 writer (k_split kernel deleted —
// saves one launch + an 8 MB re-read of x1).
__global__ __launch_bounds__(256) void k_edge1(const float* __restrict__ pm, const float* __restrict__ q,
                                               const int* __restrict__ idx1,
                                               const float* __restrict__ w2, const float* __restrict__ b2,
                                               const float* __restrict__ w3, const float* __restrict__ b3,
                                               float* __restrict__ x1, float* __restrict__ d2x1,
                                               unsigned short* __restrict__ xi)
{
    int t = threadIdx.x;
    int w = t >> 6, l = t & 63;
    int pg = l / 20;                 // group in wave (3 = idle lanes 60..63)
    int k  = l - pg * 20;
    int n0 = blockIdx.x * 12 + w * 3 + pg;
    bool valid = (l < 60) && (n0 < 32768);
    int n = valid ? n0 : 0;
    int b = n >> 12;
    int j = idx1[(size_t)n * 20 + k];
    const float4* pmr = (const float4*)(pm + (size_t)n * 64);
    const float4* qr  = (const float4*)(q + ((size_t)(b * 4096) + j) * 64);

    float h1[64];
#pragma unroll
    for (int i4 = 0; i4 < 16; ++i4) {
        float4 a = pmr[i4], c = qr[i4];
        h1[i4 * 4 + 0] = fmaxf(a.x + c.x, 0.f);
        h1[i4 * 4 + 1] = fmaxf(a.y + c.y, 0.f);
        h1[i4 * 4 + 2] = fmaxf(a.z + c.z, 0.f);
        h1[i4 * 4 + 3] = fmaxf(a.w + c.w, 0.f);
    }
    float h2[64];
#pragma unroll
    for (int o = 0; o < 64; ++o) h2[o] = b2[o];
#pragma unroll
    for (int i = 0; i < 64; ++i) {
        const float* r = w2 + i * 64;
#pragma unroll
        for (int o = 0; o < 64; ++o) h2[o] = fmaf(h1[i], r[o], h2[o]);
    }
#pragma unroll
    for (int o = 0; o < 64; ++o) h2[o] = fmaxf(h2[o], 0.f);

    float h3[64];
#pragma unroll
    for (int o = 0; o < 64; ++o) h3[o] = b3[o];
#pragma unroll
    for (int i = 0; i < 64; ++i) {
        const float* r = w3 + i * 64;
#pragma unroll
        for (int o = 0; o < 64; ++o) h3[o] = fmaf(h2[i], r[o], h3[o]);
    }

    // segmented max over the 20-lane group
    int s16 = (k + 16 < 20) ? (l + 16) : l;
    int s8  = (k + 8  < 20) ? (l + 8)  : l;
    int s4  = (k + 4  < 20) ? (l + 4)  : l;
    int s2  = (k + 2  < 20) ? (l + 2)  : l;
    int s1  = (k + 1  < 20) ? (l + 1)  : l;
#pragma unroll
    for (int o = 0; o < 64; ++o) {
        float v = h3[o];
        v = fmaxf(v, __shfl(v, s16));
        v = fmaxf(v, __shfl(v, s8));
        v = fmaxf(v, __shfl(v, s4));
        v = fmaxf(v, __shfl(v, s2));
        v = fmaxf(v, __shfl(v, s1));
        h3[o] = v;
    }
    if (valid && k == 0) {
        float d2 = 0.f;
#pragma unroll
        for (int o = 0; o < 64; ++o) d2 += h3[o] * h3[o];
        float4* op = (float4*)(x1 + (size_t)n * 64);
#pragma unroll
        for (int i4 = 0; i4 < 16; ++i4)
            op[i4] = make_float4(h3[i4 * 4], h3[i4 * 4 + 1], h3[i4 * 4 + 2], h3[i4 * 4 + 3]);
        d2x1[n] = d2;

        // fused bf16x3 split: xi[n][3][64] interleaved (identical arithmetic
        // to the old k_split — Sterbenz-exact residuals)
        size_t rb = (size_t)n * 192;
#pragma unroll
        for (int i4 = 0; i4 < 16; ++i4) {
            ub16x4 hh, mm, ll;
#pragma unroll
            for (int i = 0; i < 4; ++i) {
                float x = h3[i4 * 4 + i];
                unsigned short hb = bf16rne(x);  float fh = bf16tof(hb);
                float r1 = x - fh;
                unsigned short mb = bf16rne(r1); float fm = bf16tof(mb);
                float r2 = r1 - fm;
                unsigned short lb = bf16rne(r2);
                hh[i] = hb; mm[i] = mb; ll[i] = lb;
            }
            *(ub16x4*)(xi + rb +       i4 * 4) = hh;
            *(ub16x4*)(xi + rb +  64 + i4 * 4) = mm;
            *(ub16x4*)(xi + rb + 128 + i4 * 4) = ll;
        }
    }
}

// ---------------------------------------------------------------------------
// K3: exact-set kNN in 64-dim feature space via bf16x3 split-MFMA.
// v12 = v11 + software-pipelined candidate loads: tile T+1's 6 B-frags + d2c
// are issued AFTER tile T's MFMAs, so their L2 latency hides under the dist
// write + append + barrier instead of sitting at the head of every tile.
// Register peak ~95 < 128 cap (spill signal = FETCH/WRITE balloon — v2's
// lesson, pre-checked). Lockstep barrier per tile retained (v10's L2 fix).
// Math bit-identical to v7-v11 -> absmax 0.0.
__global__ __launch_bounds__(256, 4) void k_knn64(const unsigned short* __restrict__ xi,
                                                  const float* __restrict__ d2x1,
                                                  float* __restrict__ partD, int* __restrict__ partI)
{
    __shared__ bf16x8 qlds[1536];       // 24576 B: [pl][qb][kc][lane]
    __shared__ float dlds[4 * 16 * 64]; // 16384 B: per-wave swizzled stripes
    // total 40960 B exactly -> 4 blocks/CU

    int t = threadIdx.x;
    int blk = blockIdx.x;
    int qt = blk >> 4;                  // (b,s) in low 4 bits
    int bb = (blk >> 1) & 7;
    int s  = blk & 1;
    int qbase  = bb * 4096 + qt * 64;
    int cstart = s * 2048;
    int w = t >> 6, l = t & 63;
    int r16 = l & 15, g = l >> 4;

    // stage Q fragments once (block-shared; same lane-pattern for all waves)
    for (int f = t; f < 1536; f += 256) {
        int lane = f & 63, kc = (f >> 6) & 1, qb = (f >> 7) & 3, pl = f >> 9;
        size_t off = ((size_t)(qbase + qb * 16 + (lane & 15))) * 192 + pl * 64
                   + kc * 32 + 8 * (lane >> 4);
        qlds[f] = *(const bf16x8*)(xi + off);
    }
    float d2ql = d2x1[qbase + l];

    float bd[20]; int bi[20];
#pragma unroll
    for (int j = 0; j < 20; ++j) { bd[j] = F_INF; bi[j] = -1; }
    int cnt = 0; float thr = F_INF;
    float a0 = 0, a1 = 0, a2 = 0, a3 = 0;
    int   j0 = 0, j1 = 0, j2 = 0, j3 = 0;

    const bf16x8* qf = qlds;            // idx: ((pl*4+qb)*2+kc)*64 + l
    float* myD = dlds + w * 1024;       // wave-private 16x64 swizzled stripe

    // preload tile 0 candidate fragments
    bf16x8 bh[2], bm[2], blv[2];
    float d2cv;
    {
        int csg = bb * 4096 + cstart + 16 * w;
#pragma unroll
        for (int kc = 0; kc < 2; ++kc) {
            size_t rb = ((size_t)(csg + r16)) * 192 + kc * 32 + 8 * g;
            bh[kc]  = *(const bf16x8*)(xi + rb);
            bm[kc]  = *(const bf16x8*)(xi + rb + 64);
            blv[kc] = *(const bf16x8*)(xi + rb + 128);
        }
        d2cv = (l < 16) ? d2x1[csg + l] : 0.f;
    }
    __syncthreads();

    for (int T = 0; T < 32; ++T) {
        __syncthreads();                // per-tile lockstep (v10's L2 fix)
        int csl = cstart + T * 64 + 16 * w;     // batch-local stripe base

        floatx4 acc[4];
#pragma unroll
        for (int qb = 0; qb < 4; ++qb) acc[qb] = (floatx4){0.f, 0.f, 0.f, 0.f};
#pragma unroll
        for (int qb = 0; qb < 4; ++qb)
#pragma unroll
            for (int kc = 0; kc < 2; ++kc) {
                bf16x8 qh_ = qf[((0 * 4 + qb) * 2 + kc) * 64 + l];
                bf16x8 qm_ = qf[((1 * 4 + qb) * 2 + kc) * 64 + l];
                bf16x8 ql_ = qf[((2 * 4 + qb) * 2 + kc) * 64 + l];
                acc[qb] = __builtin_amdgcn_mfma_f32_16x16x32_bf16(qh_, bh[kc],  acc[qb], 0, 0, 0);
                acc[qb] = __builtin_amdgcn_mfma_f32_16x16x32_bf16(qh_, bm[kc],  acc[qb], 0, 0, 0);
                acc[qb] = __builtin_amdgcn_mfma_f32_16x16x32_bf16(qm_, bh[kc],  acc[qb], 0, 0, 0);
                acc[qb] = __builtin_amdgcn_mfma_f32_16x16x32_bf16(qm_, bm[kc],  acc[qb], 0, 0, 0);
                acc[qb] = __builtin_amdgcn_mfma_f32_16x16x32_bf16(qh_, blv[kc], acc[qb], 0, 0, 0);
                acc[qb] = __builtin_amdgcn_mfma_f32_16x16x32_bf16(ql_, bh[kc],  acc[qb], 0, 0, 0);
            }

        // prefetch tile T+1 candidate frags (latency hides under append)
        float d2cn = 0.f;
        if (T + 1 < 32) {
            int csg2 = bb * 4096 + cstart + (T + 1) * 64 + 16 * w;
#pragma unroll
            for (int kc = 0; kc < 2; ++kc) {
                size_t rb = ((size_t)(csg2 + r16)) * 192 + kc * 32 + 8 * g;
                bh[kc]  = *(const bf16x8*)(xi + rb);
                bm[kc]  = *(const bf16x8*)(xi + rb + 64);
                blv[kc] = *(const bf16x8*)(xi + rb + 128);
            }
            d2cn = (l < 16) ? d2x1[csg2 + l] : 0.f;
        }

        // dots -> wave-private stripe: d[cand r16][query], col-swizzled.
#pragma unroll
        for (int qb = 0; qb < 4; ++qb) {
            int colp = (qb * 16 + g * 4) ^ ((r16 & 7) << 2);
            *(floatx4*)&myD[r16 * 64 + colp] = acc[qb];
        }

        // append: lane l = query l, cands c ascending (exact list order)
#pragma unroll
        for (int c = 0; c < 16; ++c) {
            float dot = myD[c * 64 + (l ^ ((c & 7) << 2))];
            float d2c = __shfl(d2cv, c);
            float dist = (d2ql + d2c) - 2.0f * dot;
            APPEND(dist, csl + c);
        }
        d2cv = d2cn;
    }
    FLUSH();

    size_t base = (((size_t)(s * 4 + w)) * 32768 + (qbase + l)) * 20;
#pragma unroll
    for (int k = 0; k < 20; ++k) { partD[base + k] = bd[k]; partI[base + k] = bi[k]; }
}

// ---------------------------------------------------------------------------
// K4a: EdgeConv-2 full decomposition. T = x1@(Wa-Wb)+b, V = x1@Wb.
__global__ __launch_bounds__(128) void k_prep2(const float* __restrict__ x1, const float* __restrict__ w,
                                               const float* __restrict__ bias,
                                               float* __restrict__ T, float* __restrict__ V)
{
    __shared__ float xs[8][64];
    int o = threadIdx.x;
    int g = blockIdx.x * 8;
    for (int t = threadIdx.x; t < 512; t += 128) xs[t >> 6][t & 63] = x1[(size_t)g * 64 + t];
    __syncthreads();
    float at[8] = {}, av[8] = {};
    for (int i = 0; i < 64; ++i) {
        float wt = w[i * 128 + o], wv = w[(64 + i) * 128 + o];
#pragma unroll
        for (int p = 0; p < 8; ++p) {
            float xv = xs[p][i];
            at[p] = fmaf(xv, wt, at[p]);
            av[p] = fmaf(xv, wv, av[p]);
        }
    }
    float bo = bias[o];
#pragma unroll
    for (int p = 0; p < 8; ++p) {
        T[(size_t)(g + p) * 128 + o] = at[p] - av[p] + bo;
        V[(size_t)(g + p) * 128 + o] = av[p];
    }
}

// K4b: x2[n] = T[n] + max_k V[idx2[n,k]]
__global__ __launch_bounds__(256) void k_edge2(const float* __restrict__ T, const float* __restrict__ V,
                                               const int* __restrict__ idx2, float* __restrict__ x2)
{
    int t = threadIdx.x;
    int p = t >> 5, oc = t & 31;
    int n = blockIdx.x * 8 + p;
    int b = n >> 12;
    const int* ip = idx2 + (size_t)n * 20;
    float4 mx = make_float4(-F_INF, -F_INF, -F_INF, -F_INF);
    for (int k = 0; k < 20; ++k) {
        int j = ip[k];
        float4 v = ((const float4*)(V + ((size_t)(b * 4096) + j) * 128))[oc];
        mx.x = fmaxf(mx.x, v.x); mx.y = fmaxf(mx.y, v.y);
        mx.z = fmaxf(mx.z, v.z); mx.w = fmaxf(mx.w, v.w);
    }
    float4 tv = ((const float4*)(T + (size_t)n * 128))[oc];
    float4 r = make_float4(tv.x + mx.x, tv.y + mx.y, tv.z + mx.z, tv.w + mx.w);
    ((float4*)(x2 + (size_t)n * 128))[oc] = r;
}

// ---------------------------------------------------------------------------
// K5: out = max_n( [x1|x2] @ lin1_w + b ), partial max over 32-point chunks.
__global__ __launch_bounds__(256) void k_lin1max(const float* __restrict__ x1, const float* __restrict__ x2,
                                                 const float* __restrict__ w, const float* __restrict__ bias,
                                                 float* __restrict__ partial)
{
    __shared__ float fs[32][192];
    int blk = blockIdx.x;                 // 0..1023
    int b = blk >> 7, c = blk & 127;
    int base_n = b * 4096 + c * 32;
    for (int t = threadIdx.x; t < 2048; t += 256) {
        int n = t >> 6, i = t & 63;
        fs[n][i] = x1[(size_t)(base_n + n) * 64 + i];
    }
    for (int t = threadIdx.x; t < 4096; t += 256) {
        int n = t >> 7, i = t & 127;
        fs[n][64 + i] = x2[(size_t)(base_n + n) * 128 + i];
    }
    __syncthreads();

    float acc[32][4];
#pragma unroll
    for (int n = 0; n < 32; ++n)
#pragma unroll
        for (int oo = 0; oo < 4; ++oo) acc[n][oo] = 0.f;

    for (int i4 = 0; i4 < 48; ++i4) {
        float wv[4][4];
#pragma unroll
        for (int r = 0; r < 4; ++r)
#pragma unroll
            for (int oo = 0; oo < 4; ++oo)
                wv[r][oo] = w[(size_t)(i4 * 4 + r) * 1024 + oo * 256 + threadIdx.x];
#pragma unroll
        for (int n = 0; n < 32; ++n) {
            float4 f = *(const float4*)&fs[n][i4 * 4];
#pragma unroll
            for (int oo = 0; oo < 4; ++oo) {
                acc[n][oo] = fmaf(f.x, wv[0][oo], acc[n][oo]);
                acc[n][oo] = fmaf(f.y, wv[1][oo], acc[n][oo]);
                acc[n][oo] = fmaf(f.z, wv[2][oo], acc[n][oo]);
                acc[n][oo] = fmaf(f.w, wv[3][oo], acc[n][oo]);
            }
        }
    }
#pragma unroll
    for (int oo = 0; oo < 4; ++oo) {
        int o = oo * 256 + threadIdx.x;
        float m = -F_INF;
#pragma unroll
        for (int n = 0; n < 32; ++n) m = fmaxf(m, acc[n][oo]);
        partial[((size_t)b * 128 + c) * 1024 + o] = m + bias[o];
    }
}

__global__ void k_red(const float* __restrict__ partial, float* __restrict__ pooled)
{
    int t = blockIdx.x * 256 + threadIdx.x;  // 8192
    int b = t >> 10, o = t & 1023;
    float m = -F_INF;
    for (int c = 0; c < 128; ++c) m = fmaxf(m, partial[((size_t)b * 128 + c) * 1024 + o]);
    pooled[t] = m;
}

// ---------------------------------------------------------------------------
// classifier head
__global__ __launch_bounds__(256) void k_fc1(const float* __restrict__ pooled, const float* __restrict__ w,
                                             const float* __restrict__ bias, float* __restrict__ g1)
{
    __shared__ float ps[8 * 1024];
    for (int t = threadIdx.x; t < 8192; t += 256) ps[t] = pooled[t];
    __syncthreads();
    int o = blockIdx.x * 256 + threadIdx.x;   // 0..511
    float acc[8] = {};
    for (int i4 = 0; i4 < 256; ++i4) {
        float w0 = w[(size_t)(i4 * 4 + 0) * 512 + o];
        float w1v = w[(size_t)(i4 * 4 + 1) * 512 + o];
        float w2v = w[(size_t)(i4 * 4 + 2) * 512 + o];
        float w3v = w[(size_t)(i4 * 4 + 3) * 512 + o];
#pragma unroll
        for (int bb = 0; bb < 8; ++bb) {
            float4 f = *(const float4*)&ps[bb * 1024 + i4 * 4];
            acc[bb] = fmaf(f.x, w0, fmaf(f.y, w1v, fmaf(f.z, w2v, fmaf(f.w, w3v, acc[bb]))));
        }
    }
    float bo = bias[o];
#pragma unroll
    for (int bb = 0; bb < 8; ++bb) g1[bb * 512 + o] = fmaxf(acc[bb] + bo, 0.f);
}

__global__ __launch_bounds__(256) void k_fc2(const float* __restrict__ g1, const float* __restrict__ w,
                                             const float* __restrict__ bias, float* __restrict__ g2)
{
    __shared__ float gs[8 * 512];
    for (int t = threadIdx.x; t < 4096; t += 256) gs[t] = g1[t];
    __syncthreads();
    int o = threadIdx.x;                      // 0..255
    float acc[8] = {};
    for (int i4 = 0; i4 < 128; ++i4) {
        float w0 = w[(size_t)(i4 * 4 + 0) * 256 + o];
        float w1v = w[(size_t)(i4 * 4 + 1) * 256 + o];
        float w2v = w[(size_t)(i4 * 4 + 2) * 256 + o];
        float w3v = w[(size_t)(i4 * 4 + 3) * 256 + o];
#pragma unroll
        for (int bb = 0; bb < 8; ++bb) {
            float4 f = *(const float4*)&gs[bb * 512 + i4 * 4];
            acc[bb] = fmaf(f.x, w0, fmaf(f.y, w1v, fmaf(f.z, w2v, fmaf(f.w, w3v, acc[bb]))));
        }
    }
    float bo = bias[o];
#pragma unroll
    for (int bb = 0; bb < 8; ++bb) g2[bb * 256 + o] = fmaxf(acc[bb] + bo, 0.f);
}

__global__ void k_fc3sm(const float* __restrict__ g2, const float* __restrict__ w,
                        const float* __restrict__ bias, float* __restrict__ out)
{
    int t = threadIdx.x;      // 128 = 8 batches x 16 lanes
    int b = t >> 4, l = t & 15;
    float lg = -F_INF;
    if (l < 10) {
        float a = bias[l];
        for (int i = 0; i < 256; ++i) a = fmaf(g2[b * 256 + i], w[i * 10 + l], a);
        lg = a;
    }
    float m = lg;
    m = fmaxf(m, __shfl_xor(m, 1, 16));
    m = fmaxf(m, __shfl_xor(m, 2, 16));
    m = fmaxf(m, __shfl_xor(m, 4, 16));
    m = fmaxf(m, __shfl_xor(m, 8, 16));
    float e = (l < 10) ? expf(lg - m) : 0.f;
    float s = e;
    s += __shfl_xor(s, 1, 16);
    s += __shfl_xor(s, 2, 16);
    s += __shfl_xor(s, 4, 16);
    s += __shfl_xor(s, 8, 16);
    if (l < 10) out[b * 10 + l] = (lg - m) - logf(s);
}

// ---------------------------------------------------------------------------
extern "C" void kernel_launch(void* const* d_in, const int* in_sizes, int n_in,
                              void* d_out, int out_size, void* d_ws, size_t ws_size,
                              hipStream_t stream)
{
    (void)in_sizes; (void)n_in; (void)out_size; (void)ws_size;
    const float* data  = (const float*)d_in[0];
    const float* c1w1  = (const float*)d_in[1];
    const float* c1b1  = (const float*)d_in[2];
    const float* c1w2  = (const float*)d_in[3];
    const float* c1b2  = (const float*)d_in[4];
    const float* c1w3  = (const float*)d_in[5];
    const float* c1b3  = (const float*)d_in[6];
    const float* c2w1  = (const float*)d_in[7];
    const float* c2b1  = (const float*)d_in[8];
    const float* lin1w = (const float*)d_in[9];
    const float* lin1b = (const float*)d_in[10];
    const float* mw1   = (const float*)d_in[11];
    const float* mb1   = (const float*)d_in[12];
    const float* mw2   = (const float*)d_in[13];
    const float* mb2   = (const float*)d_in[14];
    const float* mw3   = (const float*)d_in[15];
    const float* mb3   = (const float*)d_in[16];
    float* ws  = (float*)d_ws;
    int*   wsi = (int*)d_ws;
    float* out = (float*)d_out;

    const size_t OFF_IDX1 = 0;          // 655360 i
    const size_t OFF_IDX2 = 0;          // 655360 i (IDX1 dead by then)
    const size_t OFF_X1   = 655360;     // 2097152 f
    const size_t OFF_D2   = 2752512;    // 32768 f
    const size_t OFF_PM   = 2785280;    // 2097152 f
    const size_t OFF_Q    = 4882432;    // 2097152 f
    const size_t OFF_PD   = 2785280;    // 5242880 f   (knn phases)
    const size_t OFF_PI   = 8028160;    // 5242880 i
    const size_t OFF_T    = 2785280;    // 4194304 f
    const size_t OFF_V    = 6979584;    // 4194304 f
    const size_t OFF_X2   = 11173888;   // 4194304 f
    const size_t OFF_PART = 15368192;   // 1048576 f
    const size_t OFF_POOL = 16416768;   // 8192 f
    const size_t OFF_G1   = 16424960;   // 4096 f
    const size_t OFF_G2   = 16429056;   // 2048 f
    // interleaved bf16x3 plane xi[32768][192]: 6291456 ushorts = 3145728
    // float-slots at [13271040, 16416768) — starts exactly at PI's end;
    // live from k_edge1 until the 2nd k_merge8, when X2/PART are still dead.
    const size_t OFF_XI   = 13271040;

    k_knn2d<<<1024, 256, 0, stream>>>(data, ws + OFF_PD, wsi + OFF_PI);
    k_merge8<<<512, 64, 0, stream>>>(ws + OFF_PD, wsi + OFF_PI, wsi + OFF_IDX1);
    k_prep1<<<8192, 256, 0, stream>>>(data, c1w1, c1b1, ws + OFF_PM, ws + OFF_Q);
    k_edge1<<<2731, 256, 0, stream>>>(ws + OFF_PM, ws + OFF_Q, wsi + OFF_IDX1,
                                      c1w2, c1b2, c1w3, c1b3, ws + OFF_X1, ws + OFF_D2,
                                      (unsigned short*)(ws + OFF_XI));
    k_knn64<<<1024, 256, 0, stream>>>((const unsigned short*)(ws + OFF_XI),
                                      ws + OFF_D2, ws + OFF_PD, wsi + OFF_PI);
    k_merge8<<<512, 64, 0, stream>>>(ws + OFF_PD, wsi + OFF_PI, wsi + OFF_IDX2);
    k_prep2<<<4096, 128, 0, stream>>>(ws + OFF_X1, c2w1, c2b1, ws + OFF_T, ws + OFF_V);
    k_edge2<<<4096, 256, 0, stream>>>(ws + OFF_T, ws + OFF_V, wsi + OFF_IDX2, ws + OFF_X2);
    k_lin1max<<<1024, 256, 0, stream>>>(ws + OFF_X1, ws + OFF_X2, lin1w, lin1b, ws + OFF_PART);
    k_red<<<32, 256, 0, stream>>>(ws + OFF_PART, ws + OFF_POOL);
    k_fc1<<<2, 256, 0, stream>>>(ws + OFF_POOL, mw1, mb1, ws + OFF_G1);
    k_fc2<<<1, 256, 0, stream>>>(ws + OFF_G1, mw2, mb2, ws + OFF_G2);
    k_fc3sm<<<1, 128, 0, stream>>>(ws + OFF_G2, mw3, mb3, out);
}

// Round 12
// 1479.992 us; speedup vs baseline: 1.0051x; 1.0051x over previous
//
#include <hip/hip_runtime.h>
#include <math.h>

#define DEVI static __device__ __forceinline__
#define F_INF __builtin_inff()

typedef short bf16x8 __attribute__((ext_vector_type(8)));    // 8 bf16 = 4 VGPR
typedef float floatx4 __attribute__((ext_vector_type(4)));   // MFMA acc
typedef unsigned short ub16x4 __attribute__((ext_vector_type(4)));

// bf16 round-to-nearest-even helpers (finite data only)
DEVI unsigned short bf16rne(float f)
{
    unsigned u = __float_as_uint(f);
    unsigned r = (u + 0x7FFFu + ((u >> 16) & 1u)) >> 16;
    return (unsigned short)r;
}
DEVI float bf16tof(unsigned short h) { return __uint_as_float(((unsigned)h) << 16); }

// ---------------------------------------------------------------------------
// Exactness scheme for kNN top-20 (set semantics — idx feeds max-pools only):
//  * each of 8 lists per query scans a disjoint candidate range in ASCENDING
//    index order, sorted top-20 with plain strict-< insertion,
//  * k_merge8 does a full (d, idx)-lexicographic tournament over the 8 lists
//    -> global top-20 set == jax.lax.top_k's set (list order irrelevant).
// bf16x3 split-MFMA dot (hh+hm+mh+mm+hl+lh): error ~2^-24 relative — verified
// absmax 0.0 end-to-end in v7-v12.
DEVI bool lexlt(float d, int i, float dr, int ir)
{
    return (d < dr) || (d == dr && i < ir);
}

// plain-< sorted insertion; (INF, any) is a guaranteed no-op.
DEVI void insert20(float* bd, int* bi, float d, int i)
{
#pragma unroll
    for (int j = 19; j >= 1; --j) {
        bool lt  = d < bd[j];
        bool ltp = d < bd[j - 1];
        float nd = ltp ? bd[j - 1] : d;
        int   ni = ltp ? bi[j - 1] : i;
        bd[j] = lt ? nd : bd[j];
        bi[j] = lt ? ni : bi[j];
    }
    bool lt0 = d < bd[0];
    bd[0] = lt0 ? d : bd[0];
    bi[0] = lt0 ? i : bi[0];
}

DEVI void insert_tiered(float* bd, int* bi, float d, int i)
{
    if (__all(!(d < bd[15]))) {
#pragma unroll
        for (int j = 19; j >= 17; --j) {
            bool lt  = d < bd[j];
            bool ltp = d < bd[j - 1];
            float nd = ltp ? bd[j - 1] : d;
            int   ni = ltp ? bi[j - 1] : i;
            bd[j] = lt ? nd : bd[j];
            bi[j] = lt ? ni : bi[j];
        }
        bool lt16 = d < bd[16];
        bd[16] = lt16 ? d : bd[16];
        bi[16] = lt16 ? i : bi[16];
    } else if (__all(!(d < bd[7]))) {
#pragma unroll
        for (int j = 19; j >= 9; --j) {
            bool lt  = d < bd[j];
            bool ltp = d < bd[j - 1];
            float nd = ltp ? bd[j - 1] : d;
            int   ni = ltp ? bi[j - 1] : i;
            bd[j] = lt ? nd : bd[j];
            bi[j] = lt ? ni : bi[j];
        }
        bool lt8 = d < bd[8];
        bd[8] = lt8 ? d : bd[8];
        bi[8] = lt8 ? i : bi[8];
    } else {
        insert20(bd, bi, d, i);
    }
}

DEVI void flushT(float* bd, int* bi, float d, int i, int e, int cnt)
{
    bool want = (e < cnt) && (d < bd[19]);
    if (__any(want))
        insert_tiered(bd, bi, want ? d : F_INF, want ? i : 0x7FFFFFFF);
}

// register append-buffer (cap 4) + wave-coupled flush
#define FLUSH() do { \
    flushT(bd, bi, a0, j0, 0, cnt); \
    flushT(bd, bi, a1, j1, 1, cnt); \
    flushT(bd, bi, a2, j2, 2, cnt); \
    flushT(bd, bi, a3, j3, 3, cnt); \
    cnt = 0; thr = bd[19]; \
} while (0)

#define APPEND(dv, civ) do { \
    bool pass_ = (dv) < thr; \
    if (pass_) { \
        a0 = (cnt == 0) ? (dv) : a0; j0 = (cnt == 0) ? (civ) : j0; \
        a1 = (cnt == 1) ? (dv) : a1; j1 = (cnt == 1) ? (civ) : j1; \
        a2 = (cnt == 2) ? (dv) : a2; j2 = (cnt == 2) ? (civ) : j2; \
        a3 = (cnt == 3) ? (dv) : a3; j3 = (cnt == 3) ? (civ) : j3; \
        ++cnt; \
    } \
    if (__any(cnt == 4)) { FLUSH(); } \
} while (0)

// ---------------------------------------------------------------------------
// K-merge: exact 8-way lex tournament. LIST-MAJOR layout —
// partD/partI[(list*32768 + q)*20 + p], list stride LS = 655360.
__global__ __launch_bounds__(64) void k_merge8(const float* __restrict__ partD,
                                               const int* __restrict__ partI,
                                               int* __restrict__ idxo)
{
    const size_t LS = 655360;           // 32768 * 20
    int q = blockIdx.x * 64 + threadIdx.x;
    const float* rd = partD + (size_t)q * 20;
    const int*   ri = partI + (size_t)q * 20;
    int p0 = 0, p1 = 0, p2 = 0, p3 = 0, p4 = 0, p5 = 0, p6 = 0, p7 = 0;
    int* op = idxo + (size_t)q * 20;
    for (int r = 0; r < 20; ++r) {      // p <= r < 20 at read time: never OOB
        float d0 = rd[p0],            d1 = rd[LS + p1];
        float d2v = rd[2 * LS + p2],  d3 = rd[3 * LS + p3];
        float d4 = rd[4 * LS + p4],   d5 = rd[5 * LS + p5];
        float d6 = rd[6 * LS + p6],   d7 = rd[7 * LS + p7];
        int   i0 = ri[p0],            i1 = ri[LS + p1];
        int   i2 = ri[2 * LS + p2],   i3 = ri[3 * LS + p3];
        int   i4v = ri[4 * LS + p4],  i5 = ri[5 * LS + p5];
        int   i6 = ri[6 * LS + p6],   i7 = ri[7 * LS + p7];
        bool wA = lexlt(d1, i1, d0, i0);   float dA = wA ? d1 : d0; int iA = wA ? i1 : i0; int sA = wA ? 1 : 0;
        bool wB = lexlt(d3, i3, d2v, i2);  float dB = wB ? d3 : d2v; int iB = wB ? i3 : i2; int sB = wB ? 3 : 2;
        bool wC = lexlt(d5, i5, d4, i4v);  float dC = wC ? d5 : d4; int iC = wC ? i5 : i4v; int sC = wC ? 5 : 4;
        bool wD = lexlt(d7, i7, d6, i6);   float dD = wD ? d7 : d6; int iD = wD ? i7 : i6; int sD = wD ? 7 : 6;
        bool wE = lexlt(dB, iB, dA, iA);   float dE = wE ? dB : dA; int iE = wE ? iB : iA; int sE = wE ? sB : sA;
        bool wF = lexlt(dD, iD, dC, iC);   float dF = wF ? dD : dC; int iF = wF ? iD : iC; int sF = wF ? sD : sC;
        bool wG = lexlt(dF, iF, dE, iE);   int ig = wG ? iF : iE;   int sg = wG ? sF : sE;
        op[r] = ig;
        p0 += (sg == 0); p1 += (sg == 1); p2 += (sg == 2); p3 += (sg == 3);
        p4 += (sg == 4); p5 += (sg == 5); p6 += (sg == 6); p7 += (sg == 7);
    }
}

// ---------------------------------------------------------------------------
// K1: exact kNN on 2D points. 1024 blocks = 8 b x 64 qtile x 2 split.
// list-major part writes.
__global__ __launch_bounds__(256, 4) void k_knn2d(const float* __restrict__ x,
                                                  float* __restrict__ partD, int* __restrict__ partI)
{
    __shared__ float2 pts[4096];
    int t = threadIdx.x;
    int blk = blockIdx.x;
    int b = blk >> 7;
    int qt = (blk >> 1) & 63;
    int s = blk & 1;
    const float* xb = x + (size_t)b * 4096 * 2;
    for (int f = t; f < 2048; f += 256)
        ((float4*)pts)[f] = ((const float4*)xb)[f];
    __syncthreads();

    int l = t & 63, w = t >> 6;
    int q = qt * 64 + l;
    float2 qp = pts[q];
    float d2i = qp.x * qp.x + qp.y * qp.y;

    float bd[20]; int bi[20];
#pragma unroll
    for (int j = 0; j < 20; ++j) { bd[j] = F_INF; bi[j] = -1; }
    int cnt = 0; float thr = F_INF;
    float a0 = 0, a1 = 0, a2 = 0, a3 = 0;
    int   j0 = 0, j1 = 0, j2 = 0, j3 = 0;

    int m0 = s * 2048 + w * 512;
    for (int m = m0; m < m0 + 512; ++m) {
        float2 p = pts[m];                       // wave-uniform -> broadcast
        float d2j = p.x * p.x + p.y * p.y;
        float dot = qp.x * p.x + qp.y * p.y;
        float dist = (d2i + d2j) - 2.0f * dot;
        APPEND(dist, m);
    }
    FLUSH();

    size_t base = (((size_t)(s * 4 + w)) * 32768 + (b * 4096 + q)) * 20;
#pragma unroll
    for (int k = 0; k < 20; ++k) { partD[base + k] = bd[k]; partI[base + k] = bi[k]; }
}

// ---------------------------------------------------------------------------
// K2a: per-point layer-1 decomposition.
__global__ void k_prep1(const float* __restrict__ x, const float* __restrict__ w1,
                        const float* __restrict__ b1, float* __restrict__ pm, float* __restrict__ qv)
{
    int tid = blockIdx.x * 256 + threadIdx.x;   // 8*4096*64
    int n = tid >> 6, i = tid & 63;
    float x0 = x[(size_t)n * 2], x1v = x[(size_t)n * 2 + 1];
    float wa = w1[i], wb = w1[64 + i], wc = w1[128 + i], wd = w1[192 + i];
    pm[tid] = fmaf(x0, wa - wc, fmaf(x1v, wb - wd, b1[i]));
    qv[tid] = fmaf(x0, wc, x1v * wd);
}

// ---------------------------------------------------------------------------
// K2: EdgeConv-1 main. 20-lane groups, segmented shuffle max.
// bf16x3 split FUSED into the k==0 writer (saves a launch + 8 MB re-read).
__global__ __launch_bounds__(256) void k_edge1(const float* __restrict__ pm, const float* __restrict__ q,
                                               const int* __restrict__ idx1,
                                               const float* __restrict__ w2, const float* __restrict__ b2,
                                               const float* __restrict__ w3, const float* __restrict__ b3,
                                               float* __restrict__ x1, float* __restrict__ d2x1,
                                               unsigned short* __restrict__ xi)
{
    int t = threadIdx.x;
    int w = t >> 6, l = t & 63;
    int pg = l / 20;                 // group in wave (3 = idle lanes 60..63)
    int k  = l - pg * 20;
    int n0 = blockIdx.x * 12 + w * 3 + pg;
    bool valid = (l < 60) && (n0 < 32768);
    int n = valid ? n0 : 0;
    int b = n >> 12;
    int j = idx1[(size_t)n * 20 + k];
    const float4* pmr = (const float4*)(pm + (size_t)n * 64);
    const float4* qr  = (const float4*)(q + ((size_t)(b * 4096) + j) * 64);

    float h1[64];
#pragma unroll
    for (int i4 = 0; i4 < 16; ++i4) {
        float4 a = pmr[i4], c = qr[i4];
        h1[i4 * 4 + 0] = fmaxf(a.x + c.x, 0.f);
        h1[i4 * 4 + 1] = fmaxf(a.y + c.y, 0.f);
        h1[i4 * 4 + 2] = fmaxf(a.z + c.z, 0.f);
        h1[i4 * 4 + 3] = fmaxf(a.w + c.w, 0.f);
    }
    float h2[64];
#pragma unroll
    for (int o = 0; o < 64; ++o) h2[o] = b2[o];
#pragma unroll
    for (int i = 0; i < 64; ++i) {
        const float* r = w2 + i * 64;
#pragma unroll
        for (int o = 0; o < 64; ++o) h2[o] = fmaf(h1[i], r[o], h2[o]);
    }
#pragma unroll
    for (int o = 0; o < 64; ++o) h2[o] = fmaxf(h2[o], 0.f);

    float h3[64];
#pragma unroll
    for (int o = 0; o < 64; ++o) h3[o] = b3[o];
#pragma unroll
    for (int i = 0; i < 64; ++i) {
        const float* r = w3 + i * 64;
#pragma unroll
        for (int o = 0; o < 64; ++o) h3[o] = fmaf(h2[i], r[o], h3[o]);
    }

    // segmented max over the 20-lane group
    int s16 = (k + 16 < 20) ? (l + 16) : l;
    int s8  = (k + 8  < 20) ? (l + 8)  : l;
    int s4  = (k + 4  < 20) ? (l + 4)  : l;
    int s2  = (k + 2  < 20) ? (l + 2)  : l;
    int s1  = (k + 1  < 20) ? (l + 1)  : l;
#pragma unroll
    for (int o = 0; o < 64; ++o) {
        float v = h3[o];
        v = fmaxf(v, __shfl(v, s16));
        v = fmaxf(v, __shfl(v, s8));
        v = fmaxf(v, __shfl(v, s4));
        v = fmaxf(v, __shfl(v, s2));
        v = fmaxf(v, __shfl(v, s1));
        h3[o] = v;
    }
    if (valid && k == 0) {
        float d2 = 0.f;
#pragma unroll
        for (int o = 0; o < 64; ++o) d2 += h3[o] * h3[o];
        float4* op = (float4*)(x1 + (size_t)n * 64);
#pragma unroll
        for (int i4 = 0; i4 < 16; ++i4)
            op[i4] = make_float4(h3[i4 * 4], h3[i4 * 4 + 1], h3[i4 * 4 + 2], h3[i4 * 4 + 3]);
        d2x1[n] = d2;

        // fused bf16x3 split: xi[n][3][64] interleaved (Sterbenz-exact)
        size_t rb = (size_t)n * 192;
#pragma unroll
        for (int i4 = 0; i4 < 16; ++i4) {
            ub16x4 hh, mm, ll;
#pragma unroll
            for (int i = 0; i < 4; ++i) {
                float x = h3[i4 * 4 + i];
                unsigned short hb = bf16rne(x);  float fh = bf16tof(hb);
                float r1 = x - fh;
                unsigned short mb = bf16rne(r1); float fm = bf16tof(mb);
                float r2 = r1 - fm;
                unsigned short lb = bf16rne(r2);
                hh[i] = hb; mm[i] = mb; ll[i] = lb;
            }
            *(ub16x4*)(xi + rb +       i4 * 4) = hh;
            *(ub16x4*)(xi + rb +  64 + i4 * 4) = mm;
            *(ub16x4*)(xi + rb + 128 + i4 * 4) = ll;
        }
    }
}

// ---------------------------------------------------------------------------
// K3: exact-set kNN in 64-dim feature space via bf16x3 split-MFMA.
// v13 = v12 pipeline + amdgpu_waves_per_eu(4,4). v12's spill: the allocator
// targeted the 8-waves/SIMD budget (64 VGPR) despite LDS capping the block at
// 4 waves/SIMD, so the 25 prefetch VGPRs went to scratch (WRITE 44->366 MB).
// Pinning waves/EU to exactly 4 raises the budget to 128 — the prefetch
// window fits in registers and the software pipeline works as designed.
// Math bit-identical to v7-v12 -> absmax 0.0.
__global__ __launch_bounds__(256)
__attribute__((amdgpu_waves_per_eu(4, 4)))
void k_knn64(const unsigned short* __restrict__ xi,
             const float* __restrict__ d2x1,
             float* __restrict__ partD, int* __restrict__ partI)
{
    __shared__ bf16x8 qlds[1536];       // 24576 B: [pl][qb][kc][lane]
    __shared__ float dlds[4 * 16 * 64]; // 16384 B: per-wave swizzled stripes
    // total 40960 B exactly -> 4 blocks/CU

    int t = threadIdx.x;
    int blk = blockIdx.x;
    int qt = blk >> 4;                  // (b,s) in low 4 bits
    int bb = (blk >> 1) & 7;
    int s  = blk & 1;
    int qbase  = bb * 4096 + qt * 64;
    int cstart = s * 2048;
    int w = t >> 6, l = t & 63;
    int r16 = l & 15, g = l >> 4;

    // stage Q fragments once (block-shared; same lane-pattern for all waves)
    for (int f = t; f < 1536; f += 256) {
        int lane = f & 63, kc = (f >> 6) & 1, qb = (f >> 7) & 3, pl = f >> 9;
        size_t off = ((size_t)(qbase + qb * 16 + (lane & 15))) * 192 + pl * 64
                   + kc * 32 + 8 * (lane >> 4);
        qlds[f] = *(const bf16x8*)(xi + off);
    }
    float d2ql = d2x1[qbase + l];

    float bd[20]; int bi[20];
#pragma unroll
    for (int j = 0; j < 20; ++j) { bd[j] = F_INF; bi[j] = -1; }
    int cnt = 0; float thr = F_INF;
    float a0 = 0, a1 = 0, a2 = 0, a3 = 0;
    int   j0 = 0, j1 = 0, j2 = 0, j3 = 0;

    const bf16x8* qf = qlds;            // idx: ((pl*4+qb)*2+kc)*64 + l
    float* myD = dlds + w * 1024;       // wave-private 16x64 swizzled stripe

    // preload tile 0 candidate fragments
    bf16x8 bh[2], bm[2], blv[2];
    float d2cv;
    {
        int csg = bb * 4096 + cstart + 16 * w;
#pragma unroll
        for (int kc = 0; kc < 2; ++kc) {
            size_t rb = ((size_t)(csg + r16)) * 192 + kc * 32 + 8 * g;
            bh[kc]  = *(const bf16x8*)(xi + rb);
            bm[kc]  = *(const bf16x8*)(xi + rb + 64);
            blv[kc] = *(const bf16x8*)(xi + rb + 128);
        }
        d2cv = (l < 16) ? d2x1[csg + l] : 0.f;
    }
    __syncthreads();

    for (int T = 0; T < 32; ++T) {
        __syncthreads();                // per-tile lockstep (v10's L2 fix)
        int csl = cstart + T * 64 + 16 * w;     // batch-local stripe base

        floatx4 acc[4];
#pragma unroll
        for (int qb = 0; qb < 4; ++qb) acc[qb] = (floatx4){0.f, 0.f, 0.f, 0.f};
#pragma unroll
        for (int qb = 0; qb < 4; ++qb)
#pragma unroll
            for (int kc = 0; kc < 2; ++kc) {
                bf16x8 qh_ = qf[((0 * 4 + qb) * 2 + kc) * 64 + l];
                bf16x8 qm_ = qf[((1 * 4 + qb) * 2 + kc) * 64 + l];
                bf16x8 ql_ = qf[((2 * 4 + qb) * 2 + kc) * 64 + l];
                acc[qb] = __builtin_amdgcn_mfma_f32_16x16x32_bf16(qh_, bh[kc],  acc[qb], 0, 0, 0);
                acc[qb] = __builtin_amdgcn_mfma_f32_16x16x32_bf16(qh_, bm[kc],  acc[qb], 0, 0, 0);
                acc[qb] = __builtin_amdgcn_mfma_f32_16x16x32_bf16(qm_, bh[kc],  acc[qb], 0, 0, 0);
                acc[qb] = __builtin_amdgcn_mfma_f32_16x16x32_bf16(qm_, bm[kc],  acc[qb], 0, 0, 0);
                acc[qb] = __builtin_amdgcn_mfma_f32_16x16x32_bf16(qh_, blv[kc], acc[qb], 0, 0, 0);
                acc[qb] = __builtin_amdgcn_mfma_f32_16x16x32_bf16(ql_, bh[kc],  acc[qb], 0, 0, 0);
            }

        // prefetch tile T+1 candidate frags (latency hides under append)
        float d2cn = 0.f;
        if (T + 1 < 32) {
            int csg2 = bb * 4096 + cstart + (T + 1) * 64 + 16 * w;
#pragma unroll
            for (int kc = 0; kc < 2; ++kc) {
                size_t rb = ((size_t)(csg2 + r16)) * 192 + kc * 32 + 8 * g;
                bh[kc]  = *(const bf16x8*)(xi + rb);
                bm[kc]  = *(const bf16x8*)(xi + rb + 64);
                blv[kc] = *(const bf16x8*)(xi + rb + 128);
            }
            d2cn = (l < 16) ? d2x1[csg2 + l] : 0.f;
        }

        // dots -> wave-private stripe: d[cand r16][query], col-swizzled.
#pragma unroll
        for (int qb = 0; qb < 4; ++qb) {
            int colp = (qb * 16 + g * 4) ^ ((r16 & 7) << 2);
            *(floatx4*)&myD[r16 * 64 + colp] = acc[qb];
        }

        // append: lane l = query l, cands c ascending (exact list order)
#pragma unroll
        for (int c = 0; c < 16; ++c) {
            float dot = myD[c * 64 + (l ^ ((c & 7) << 2))];
            float d2c = __shfl(d2cv, c);
            float dist = (d2ql + d2c) - 2.0f * dot;
            APPEND(dist, csl + c);
        }
        d2cv = d2cn;
    }
    FLUSH();

    size_t base = (((size_t)(s * 4 + w)) * 32768 + (qbase + l)) * 20;
#pragma unroll
    for (int k = 0; k < 20; ++k) { partD[base + k] = bd[k]; partI[base + k] = bi[k]; }
}

// ---------------------------------------------------------------------------
// K4a: EdgeConv-2 full decomposition. T = x1@(Wa-Wb)+b, V = x1@Wb.
__global__ __launch_bounds__(128) void k_prep2(const float* __restrict__ x1, const float* __restrict__ w,
                                               const float* __restrict__ bias,
                                               float* __restrict__ T, float* __restrict__ V)
{
    __shared__ float xs[8][64];
    int o = threadIdx.x;
    int g = blockIdx.x * 8;
    for (int t = threadIdx.x; t < 512; t += 128) xs[t >> 6][t & 63] = x1[(size_t)g * 64 + t];
    __syncthreads();
    float at[8] = {}, av[8] = {};
    for (int i = 0; i < 64; ++i) {
        float wt = w[i * 128 + o], wv = w[(64 + i) * 128 + o];
#pragma unroll
        for (int p = 0; p < 8; ++p) {
            float xv = xs[p][i];
            at[p] = fmaf(xv, wt, at[p]);
            av[p] = fmaf(xv, wv, av[p]);
        }
    }
    float bo = bias[o];
#pragma unroll
    for (int p = 0; p < 8; ++p) {
        T[(size_t)(g + p) * 128 + o] = at[p] - av[p] + bo;
        V[(size_t)(g + p) * 128 + o] = av[p];
    }
}

// K4b: x2[n] = T[n] + max_k V[idx2[n,k]]
__global__ __launch_bounds__(256) void k_edge2(const float* __restrict__ T, const float* __restrict__ V,
                                               const int* __restrict__ idx2, float* __restrict__ x2)
{
    int t = threadIdx.x;
    int p = t >> 5, oc = t & 31;
    int n = blockIdx.x * 8 + p;
    int b = n >> 12;
    const int* ip = idx2 + (size_t)n * 20;
    float4 mx = make_float4(-F_INF, -F_INF, -F_INF, -F_INF);
    for (int k = 0; k < 20; ++k) {
        int j = ip[k];
        float4 v = ((const float4*)(V + ((size_t)(b * 4096) + j) * 128))[oc];
        mx.x = fmaxf(mx.x, v.x); mx.y = fmaxf(mx.y, v.y);
        mx.z = fmaxf(mx.z, v.z); mx.w = fmaxf(mx.w, v.w);
    }
    float4 tv = ((const float4*)(T + (size_t)n * 128))[oc];
    float4 r = make_float4(tv.x + mx.x, tv.y + mx.y, tv.z + mx.z, tv.w + mx.w);
    ((float4*)(x2 + (size_t)n * 128))[oc] = r;
}

// ---------------------------------------------------------------------------
// K5: out = max_n( [x1|x2] @ lin1_w + b ), partial max over 32-point chunks.
__global__ __launch_bounds__(256) void k_lin1max(const float* __restrict__ x1, const float* __restrict__ x2,
                                                 const float* __restrict__ w, const float* __restrict__ bias,
                                                 float* __restrict__ partial)
{
    __shared__ float fs[32][192];
    int blk = blockIdx.x;                 // 0..1023
    int b = blk >> 7, c = blk & 127;
    int base_n = b * 4096 + c * 32;
    for (int t = threadIdx.x; t < 2048; t += 256) {
        int n = t >> 6, i = t & 63;
        fs[n][i] = x1[(size_t)(base_n + n) * 64 + i];
    }
    for (int t = threadIdx.x; t < 4096; t += 256) {
        int n = t >> 7, i = t & 127;
        fs[n][64 + i] = x2[(size_t)(base_n + n) * 128 + i];
    }
    __syncthreads();

    float acc[32][4];
#pragma unroll
    for (int n = 0; n < 32; ++n)
#pragma unroll
        for (int oo = 0; oo < 4; ++oo) acc[n][oo] = 0.f;

    for (int i4 = 0; i4 < 48; ++i4) {
        float wv[4][4];
#pragma unroll
        for (int r = 0; r < 4; ++r)
#pragma unroll
            for (int oo = 0; oo < 4; ++oo)
                wv[r][oo] = w[(size_t)(i4 * 4 + r) * 1024 + oo * 256 + threadIdx.x];
#pragma unroll
        for (int n = 0; n < 32; ++n) {
            float4 f = *(const float4*)&fs[n][i4 * 4];
#pragma unroll
            for (int oo = 0; oo < 4; ++oo) {
                acc[n][oo] = fmaf(f.x, wv[0][oo], acc[n][oo]);
                acc[n][oo] = fmaf(f.y, wv[1][oo], acc[n][oo]);
                acc[n][oo] = fmaf(f.z, wv[2][oo], acc[n][oo]);
                acc[n][oo] = fmaf(f.w, wv[3][oo], acc[n][oo]);
            }
        }
    }
#pragma unroll
    for (int oo = 0; oo < 4; ++oo) {
        int o = oo * 256 + threadIdx.x;
        float m = -F_INF;
#pragma unroll
        for (int n = 0; n < 32; ++n) m = fmaxf(m, acc[n][oo]);
        partial[((size_t)b * 128 + c) * 1024 + o] = m + bias[o];
    }
}

__global__ void k_red(const float* __restrict__ partial, float* __restrict__ pooled)
{
    int t = blockIdx.x * 256 + threadIdx.x;  // 8192
    int b = t >> 10, o = t & 1023;
    float m = -F_INF;
    for (int c = 0; c < 128; ++c) m = fmaxf(m, partial[((size_t)b * 128 + c) * 1024 + o]);
    pooled[t] = m;
}

// ---------------------------------------------------------------------------
// classifier head
__global__ __launch_bounds__(256) void k_fc1(const float* __restrict__ pooled, const float* __restrict__ w,
                                             const float* __restrict__ bias, float* __restrict__ g1)
{
    __shared__ float ps[8 * 1024];
    for (int t = threadIdx.x; t < 8192; t += 256) ps[t] = pooled[t];
    __syncthreads();
    int o = blockIdx.x * 256 + threadIdx.x;   // 0..511
    float acc[8] = {};
    for (int i4 = 0; i4 < 256; ++i4) {
        float w0 = w[(size_t)(i4 * 4 + 0) * 512 + o];
        float w1v = w[(size_t)(i4 * 4 + 1) * 512 + o];
        float w2v = w[(size_t)(i4 * 4 + 2) * 512 + o];
        float w3v = w[(size_t)(i4 * 4 + 3) * 512 + o];
#pragma unroll
        for (int bb = 0; bb < 8; ++bb) {
            float4 f = *(const float4*)&ps[bb * 1024 + i4 * 4];
            acc[bb] = fmaf(f.x, w0, fmaf(f.y, w1v, fmaf(f.z, w2v, fmaf(f.w, w3v, acc[bb]))));
        }
    }
    float bo = bias[o];
#pragma unroll
    for (int bb = 0; bb < 8; ++bb) g1[bb * 512 + o] = fmaxf(acc[bb] + bo, 0.f);
}

__global__ __launch_bounds__(256) void k_fc2(const float* __restrict__ g1, const float* __restrict__ w,
                                             const float* __restrict__ bias, float* __restrict__ g2)
{
    __shared__ float gs[8 * 512];
    for (int t = threadIdx.x; t < 4096; t += 256) gs[t] = g1[t];
    __syncthreads();
    int o = threadIdx.x;                      // 0..255
    float acc[8] = {};
    for (int i4 = 0; i4 < 128; ++i4) {
        float w0 = w[(size_t)(i4 * 4 + 0) * 256 + o];
        float w1v = w[(size_t)(i4 * 4 + 1) * 256 + o];
        float w2v = w[(size_t)(i4 * 4 + 2) * 256 + o];
        float w3v = w[(size_t)(i4 * 4 + 3) * 256 + o];
#pragma unroll
        for (int bb = 0; bb < 8; ++bb) {
            float4 f = *(const float4*)&gs[bb * 512 + i4 * 4];
            acc[bb] = fmaf(f.x, w0, fmaf(f.y, w1v, fmaf(f.z, w2v, fmaf(f.w, w3v, acc[bb]))));
        }
    }
    float bo = bias[o];
#pragma unroll
    for (int bb = 0; bb < 8; ++bb) g2[bb * 256 + o] = fmaxf(acc[bb] + bo, 0.f);
}

__global__ void k_fc3sm(const float* __restrict__ g2, const float* __restrict__ w,
                        const float* __restrict__ bias, float* __restrict__ out)
{
    int t = threadIdx.x;      // 128 = 8 batches x 16 lanes
    int b = t >> 4, l = t & 15;
    float lg = -F_INF;
    if (l < 10) {
        float a = bias[l];
        for (int i = 0; i < 256; ++i) a = fmaf(g2[b * 256 + i], w[i * 10 + l], a);
        lg = a;
    }
    float m = lg;
    m = fmaxf(m, __shfl_xor(m, 1, 16));
    m = fmaxf(m, __shfl_xor(m, 2, 16));
    m = fmaxf(m, __shfl_xor(m, 4, 16));
    m = fmaxf(m, __shfl_xor(m, 8, 16));
    float e = (l < 10) ? expf(lg - m) : 0.f;
    float s = e;
    s += __shfl_xor(s, 1, 16);
    s += __shfl_xor(s, 2, 16);
    s += __shfl_xor(s, 4, 16);
    s += __shfl_xor(s, 8, 16);
    if (l < 10) out[b * 10 + l] = (lg - m) - logf(s);
}

// ---------------------------------------------------------------------------
extern "C" void kernel_launch(void* const* d_in, const int* in_sizes, int n_in,
                              void* d_out, int out_size, void* d_ws, size_t ws_size,
                              hipStream_t stream)
{
    (void)in_sizes; (void)n_in; (void)out_size; (void)ws_size;
    const float* data  = (const float*)d_in[0];
    const float* c1w1  = (const float*)d_in[1];
    const float* c1b1  = (const float*)d_in[2];
    const float* c1w2  = (const float*)d_in[3];
    const float* c1b2  = (const float*)d_in[4];
    const float* c1w3  = (const float*)d_in[5];
    const float* c1b3  = (const float*)d_in[6];
    const float* c2w1  = (const float*)d_in[7];
    const float* c2b1  = (const float*)d_in[8];
    const float* lin1w = (const float*)d_in[9];
    const float* lin1b = (const float*)d_in[10];
    const float* mw1   = (const float*)d_in[11];
    const float* mb1   = (const float*)d_in[12];
    const float* mw2   = (const float*)d_in[13];
    const float* mb2   = (const float*)d_in[14];
    const float* mw3   = (const float*)d_in[15];
    const float* mb3   = (const float*)d_in[16];
    float* ws  = (float*)d_ws;
    int*   wsi = (int*)d_ws;
    float* out = (float*)d_out;

    const size_t OFF_IDX1 = 0;          // 655360 i
    const size_t OFF_IDX2 = 0;          // 655360 i (IDX1 dead by then)
    const size_t OFF_X1   = 655360;     // 2097152 f
    const size_t OFF_D2   = 2752512;    // 32768 f
    const size_t OFF_PM   = 2785280;    // 2097152 f
    const size_t OFF_Q    = 4882432;    // 2097152 f
    const size_t OFF_PD   = 2785280;    // 5242880 f   (knn phases)
    const size_t OFF_PI   = 8028160;    // 5242880 i
    const size_t OFF_T    = 2785280;    // 4194304 f
    const size_t OFF_V    = 6979584;    // 4194304 f
    const size_t OFF_X2   = 11173888;   // 4194304 f
    const size_t OFF_PART = 15368192;   // 1048576 f
    const size_t OFF_POOL = 16416768;   // 8192 f
    const size_t OFF_G1   = 16424960;   // 4096 f
    const size_t OFF_G2   = 16429056;   // 2048 f
    // interleaved bf16x3 plane xi[32768][192]: 6291456 ushorts = 3145728
    // float-slots at [13271040, 16416768) — live from k_edge1 until the 2nd
    // k_merge8; X2/PART are dead during that window.
    const size_t OFF_XI   = 13271040;

    k_knn2d<<<1024, 256, 0, stream>>>(data, ws + OFF_PD, wsi + OFF_PI);
    k_merge8<<<512, 64, 0, stream>>>(ws + OFF_PD, wsi + OFF_PI, wsi + OFF_IDX1);
    k_prep1<<<8192, 256, 0, stream>>>(data, c1w1, c1b1, ws + OFF_PM, ws + OFF_Q);
    k_edge1<<<2731, 256, 0, stream>>>(ws + OFF_PM, ws + OFF_Q, wsi + OFF_IDX1,
                                      c1w2, c1b2, c1w3, c1b3, ws + OFF_X1, ws + OFF_D2,
                                      (unsigned short*)(ws + OFF_XI));
    k_knn64<<<1024, 256, 0, stream>>>((const unsigned short*)(ws + OFF_XI),
                                      ws + OFF_D2, ws + OFF_PD, wsi + OFF_PI);
    k_merge8<<<512, 64, 0, stream>>>(ws + OFF_PD, wsi + OFF_PI, wsi + OFF_IDX2);
    k_prep2<<<4096, 128, 0, stream>>>(ws + OFF_X1, c2w1, c2b1, ws + OFF_T, ws + OFF_V);
    k_edge2<<<4096, 256, 0, stream>>>(ws + OFF_T, ws + OFF_V, wsi + OFF_IDX2, ws + OFF_X2);
    k_lin1max<<<1024, 256, 0, stream>>>(ws + OFF_X1, ws + OFF_X2, lin1w, lin1b, ws + OFF_PART);
    k_red<<<32, 256, 0, stream>>>(ws + OFF_PART, ws + OFF_POOL);
    k_fc1<<<2, 256, 0, stream>>>(ws + OFF_POOL, mw1, mb1, ws + OFF_G1);
    k_fc2<<<1, 256, 0, stream>>>(ws + OFF_G1, mw2, mb2, ws + OFF_G2);
    k_fc3sm<<<1, 128, 0, stream>>>(ws + OFF_G2, mw3, mb3, out);
}

// Round 13
// 1416.242 us; speedup vs baseline: 1.0503x; 1.0450x over previous
//
#include <hip/hip_runtime.h>
#include <math.h>

#define DEVI static __device__ __forceinline__
#define F_INF __builtin_inff()

typedef short bf16x8 __attribute__((ext_vector_type(8)));    // 8 bf16 = 4 VGPR
typedef float floatx4 __attribute__((ext_vector_type(4)));   // MFMA acc
typedef unsigned short ub16x4 __attribute__((ext_vector_type(4)));

// bf16 round-to-nearest-even helpers (finite data only)
DEVI unsigned short bf16rne(float f)
{
    unsigned u = __float_as_uint(f);
    unsigned r = (u + 0x7FFFu + ((u >> 16) & 1u)) >> 16;
    return (unsigned short)r;
}
DEVI float bf16tof(unsigned short h) { return __uint_as_float(((unsigned)h) << 16); }

// ---------------------------------------------------------------------------
// Exactness scheme for kNN top-20 (set semantics — idx feeds max-pools only):
//  * each of 8 lists per query scans a disjoint candidate range in ASCENDING
//    index order, sorted top-20 with plain strict-< insertion,
//  * k_merge8 does a full (d, idx)-lexicographic tournament over the 8 lists
//    -> global top-20 set == jax.lax.top_k's set (list order irrelevant).
// bf16x3 split-MFMA dot (hh+hm+mh+mm+hl+lh): error ~2^-24 relative — verified
// absmax 0.0 end-to-end in v7-v13.
DEVI bool lexlt(float d, int i, float dr, int ir)
{
    return (d < dr) || (d == dr && i < ir);
}

// plain-< sorted insertion; (INF, any) is a guaranteed no-op.
DEVI void insert20(float* bd, int* bi, float d, int i)
{
#pragma unroll
    for (int j = 19; j >= 1; --j) {
        bool lt  = d < bd[j];
        bool ltp = d < bd[j - 1];
        float nd = ltp ? bd[j - 1] : d;
        int   ni = ltp ? bi[j - 1] : i;
        bd[j] = lt ? nd : bd[j];
        bi[j] = lt ? ni : bi[j];
    }
    bool lt0 = d < bd[0];
    bd[0] = lt0 ? d : bd[0];
    bi[0] = lt0 ? i : bi[0];
}

DEVI void insert_tiered(float* bd, int* bi, float d, int i)
{
    if (__all(!(d < bd[15]))) {
#pragma unroll
        for (int j = 19; j >= 17; --j) {
            bool lt  = d < bd[j];
            bool ltp = d < bd[j - 1];
            float nd = ltp ? bd[j - 1] : d;
            int   ni = ltp ? bi[j - 1] : i;
            bd[j] = lt ? nd : bd[j];
            bi[j] = lt ? ni : bi[j];
        }
        bool lt16 = d < bd[16];
        bd[16] = lt16 ? d : bd[16];
        bi[16] = lt16 ? i : bi[16];
    } else if (__all(!(d < bd[7]))) {
#pragma unroll
        for (int j = 19; j >= 9; --j) {
            bool lt  = d < bd[j];
            bool ltp = d < bd[j - 1];
            float nd = ltp ? bd[j - 1] : d;
            int   ni = ltp ? bi[j - 1] : i;
            bd[j] = lt ? nd : bd[j];
            bi[j] = lt ? ni : bi[j];
        }
        bool lt8 = d < bd[8];
        bd[8] = lt8 ? d : bd[8];
        bi[8] = lt8 ? i : bi[8];
    } else {
        insert20(bd, bi, d, i);
    }
}

DEVI void flushT(float* bd, int* bi, float d, int i, int e, int cnt)
{
    bool want = (e < cnt) && (d < bd[19]);
    if (__any(want))
        insert_tiered(bd, bi, want ? d : F_INF, want ? i : 0x7FFFFFFF);
}

// register append-buffer (cap 4) + wave-coupled flush
#define FLUSH() do { \
    flushT(bd, bi, a0, j0, 0, cnt); \
    flushT(bd, bi, a1, j1, 1, cnt); \
    flushT(bd, bi, a2, j2, 2, cnt); \
    flushT(bd, bi, a3, j3, 3, cnt); \
    cnt = 0; thr = bd[19]; \
} while (0)

#define APPEND(dv, civ) do { \
    bool pass_ = (dv) < thr; \
    if (pass_) { \
        a0 = (cnt == 0) ? (dv) : a0; j0 = (cnt == 0) ? (civ) : j0; \
        a1 = (cnt == 1) ? (dv) : a1; j1 = (cnt == 1) ? (civ) : j1; \
        a2 = (cnt == 2) ? (dv) : a2; j2 = (cnt == 2) ? (civ) : j2; \
        a3 = (cnt == 3) ? (dv) : a3; j3 = (cnt == 3) ? (civ) : j3; \
        ++cnt; \
    } \
    if (__any(cnt == 4)) { FLUSH(); } \
} while (0)

// ---------------------------------------------------------------------------
// K-merge: exact 8-way lex tournament. LIST-MAJOR layout —
// partD/partI[(list*32768 + q)*20 + p], list stride LS = 655360.
__global__ __launch_bounds__(64) void k_merge8(const float* __restrict__ partD,
                                               const int* __restrict__ partI,
                                               int* __restrict__ idxo)
{
    const size_t LS = 655360;           // 32768 * 20
    int q = blockIdx.x * 64 + threadIdx.x;
    const float* rd = partD + (size_t)q * 20;
    const int*   ri = partI + (size_t)q * 20;
    int p0 = 0, p1 = 0, p2 = 0, p3 = 0, p4 = 0, p5 = 0, p6 = 0, p7 = 0;
    int* op = idxo + (size_t)q * 20;
    for (int r = 0; r < 20; ++r) {      // p <= r < 20 at read time: never OOB
        float d0 = rd[p0],            d1 = rd[LS + p1];
        float d2v = rd[2 * LS + p2],  d3 = rd[3 * LS + p3];
        float d4 = rd[4 * LS + p4],   d5 = rd[5 * LS + p5];
        float d6 = rd[6 * LS + p6],   d7 = rd[7 * LS + p7];
        int   i0 = ri[p0],            i1 = ri[LS + p1];
        int   i2 = ri[2 * LS + p2],   i3 = ri[3 * LS + p3];
        int   i4v = ri[4 * LS + p4],  i5 = ri[5 * LS + p5];
        int   i6 = ri[6 * LS + p6],   i7 = ri[7 * LS + p7];
        bool wA = lexlt(d1, i1, d0, i0);   float dA = wA ? d1 : d0; int iA = wA ? i1 : i0; int sA = wA ? 1 : 0;
        bool wB = lexlt(d3, i3, d2v, i2);  float dB = wB ? d3 : d2v; int iB = wB ? i3 : i2; int sB = wB ? 3 : 2;
        bool wC = lexlt(d5, i5, d4, i4v);  float dC = wC ? d5 : d4; int iC = wC ? i5 : i4v; int sC = wC ? 5 : 4;
        bool wD = lexlt(d7, i7, d6, i6);   float dD = wD ? d7 : d6; int iD = wD ? i7 : i6; int sD = wD ? 7 : 6;
        bool wE = lexlt(dB, iB, dA, iA);   float dE = wE ? dB : dA; int iE = wE ? iB : iA; int sE = wE ? sB : sA;
        bool wF = lexlt(dD, iD, dC, iC);   float dF = wF ? dD : dC; int iF = wF ? iD : iC; int sF = wF ? sD : sC;
        bool wG = lexlt(dF, iF, dE, iE);   int ig = wG ? iF : iE;   int sg = wG ? sF : sE;
        op[r] = ig;
        p0 += (sg == 0); p1 += (sg == 1); p2 += (sg == 2); p3 += (sg == 3);
        p4 += (sg == 4); p5 += (sg == 5); p6 += (sg == 6); p7 += (sg == 7);
    }
}

// ---------------------------------------------------------------------------
// K1: exact kNN on 2D points. 1024 blocks = 8 b x 64 qtile x 2 split.
// list-major part writes.
__global__ __launch_bounds__(256, 4) void k_knn2d(const float* __restrict__ x,
                                                  float* __restrict__ partD, int* __restrict__ partI)
{
    __shared__ float2 pts[4096];
    int t = threadIdx.x;
    int blk = blockIdx.x;
    int b = blk >> 7;
    int qt = (blk >> 1) & 63;
    int s = blk & 1;
    const float* xb = x + (size_t)b * 4096 * 2;
    for (int f = t; f < 2048; f += 256)
        ((float4*)pts)[f] = ((const float4*)xb)[f];
    __syncthreads();

    int l = t & 63, w = t >> 6;
    int q = qt * 64 + l;
    float2 qp = pts[q];
    float d2i = qp.x * qp.x + qp.y * qp.y;

    float bd[20]; int bi[20];
#pragma unroll
    for (int j = 0; j < 20; ++j) { bd[j] = F_INF; bi[j] = -1; }
    int cnt = 0; float thr = F_INF;
    float a0 = 0, a1 = 0, a2 = 0, a3 = 0;
    int   j0 = 0, j1 = 0, j2 = 0, j3 = 0;

    int m0 = s * 2048 + w * 512;
    for (int m = m0; m < m0 + 512; ++m) {
        float2 p = pts[m];                       // wave-uniform -> broadcast
        float d2j = p.x * p.x + p.y * p.y;
        float dot = qp.x * p.x + qp.y * p.y;
        float dist = (d2i + d2j) - 2.0f * dot;
        APPEND(dist, m);
    }
    FLUSH();

    size_t base = (((size_t)(s * 4 + w)) * 32768 + (b * 4096 + q)) * 20;
#pragma unroll
    for (int k = 0; k < 20; ++k) { partD[base + k] = bd[k]; partI[base + k] = bi[k]; }
}

// ---------------------------------------------------------------------------
// K2a: per-point layer-1 decomposition.
__global__ void k_prep1(const float* __restrict__ x, const float* __restrict__ w1,
                        const float* __restrict__ b1, float* __restrict__ pm, float* __restrict__ qv)
{
    int tid = blockIdx.x * 256 + threadIdx.x;   // 8*4096*64
    int n = tid >> 6, i = tid & 63;
    float x0 = x[(size_t)n * 2], x1v = x[(size_t)n * 2 + 1];
    float wa = w1[i], wb = w1[64 + i], wc = w1[128 + i], wd = w1[192 + i];
    pm[tid] = fmaf(x0, wa - wc, fmaf(x1v, wb - wd, b1[i]));
    qv[tid] = fmaf(x0, wc, x1v * wd);
}

// ---------------------------------------------------------------------------
// K2: EdgeConv-1 main. 20-lane groups, segmented shuffle max.
// bf16x3 split FUSED into the k==0 writer (saves a launch + 8 MB re-read).
__global__ __launch_bounds__(256) void k_edge1(const float* __restrict__ pm, const float* __restrict__ q,
                                               const int* __restrict__ idx1,
                                               const float* __restrict__ w2, const float* __restrict__ b2,
                                               const float* __restrict__ w3, const float* __restrict__ b3,
                                               float* __restrict__ x1, float* __restrict__ d2x1,
                                               unsigned short* __restrict__ xi)
{
    int t = threadIdx.x;
    int w = t >> 6, l = t & 63;
    int pg = l / 20;                 // group in wave (3 = idle lanes 60..63)
    int k  = l - pg * 20;
    int n0 = blockIdx.x * 12 + w * 3 + pg;
    bool valid = (l < 60) && (n0 < 32768);
    int n = valid ? n0 : 0;
    int b = n >> 12;
    int j = idx1[(size_t)n * 20 + k];
    const float4* pmr = (const float4*)(pm + (size_t)n * 64);
    const float4* qr  = (const float4*)(q + ((size_t)(b * 4096) + j) * 64);

    float h1[64];
#pragma unroll
    for (int i4 = 0; i4 < 16; ++i4) {
        float4 a = pmr[i4], c = qr[i4];
        h1[i4 * 4 + 0] = fmaxf(a.x + c.x, 0.f);
        h1[i4 * 4 + 1] = fmaxf(a.y + c.y, 0.f);
        h1[i4 * 4 + 2] = fmaxf(a.z + c.z, 0.f);
        h1[i4 * 4 + 3] = fmaxf(a.w + c.w, 0.f);
    }
    float h2[64];
#pragma unroll
    for (int o = 0; o < 64; ++o) h2[o] = b2[o];
#pragma unroll
    for (int i = 0; i < 64; ++i) {
        const float* r = w2 + i * 64;       // wave-uniform -> scalar loads
#pragma unroll
        for (int o = 0; o < 64; ++o) h2[o] = fmaf(h1[i], r[o], h2[o]);
    }
#pragma unroll
    for (int o = 0; o < 64; ++o) h2[o] = fmaxf(h2[o], 0.f);

    float h3[64];
#pragma unroll
    for (int o = 0; o < 64; ++o) h3[o] = b3[o];
#pragma unroll
    for (int i = 0; i < 64; ++i) {
        const float* r = w3 + i * 64;
#pragma unroll
        for (int o = 0; o < 64; ++o) h3[o] = fmaf(h2[i], r[o], h3[o]);
    }

    // segmented max over the 20-lane group
    int s16 = (k + 16 < 20) ? (l + 16) : l;
    int s8  = (k + 8  < 20) ? (l + 8)  : l;
    int s4  = (k + 4  < 20) ? (l + 4)  : l;
    int s2  = (k + 2  < 20) ? (l + 2)  : l;
    int s1  = (k + 1  < 20) ? (l + 1)  : l;
#pragma unroll
    for (int o = 0; o < 64; ++o) {
        float v = h3[o];
        v = fmaxf(v, __shfl(v, s16));
        v = fmaxf(v, __shfl(v, s8));
        v = fmaxf(v, __shfl(v, s4));
        v = fmaxf(v, __shfl(v, s2));
        v = fmaxf(v, __shfl(v, s1));
        h3[o] = v;
    }
    if (valid && k == 0) {
        float d2 = 0.f;
#pragma unroll
        for (int o = 0; o < 64; ++o) d2 += h3[o] * h3[o];
        float4* op = (float4*)(x1 + (size_t)n * 64);
#pragma unroll
        for (int i4 = 0; i4 < 16; ++i4)
            op[i4] = make_float4(h3[i4 * 4], h3[i4 * 4 + 1], h3[i4 * 4 + 2], h3[i4 * 4 + 3]);
        d2x1[n] = d2;

        // fused bf16x3 split: xi[n][3][64] interleaved (Sterbenz-exact)
        size_t rb = (size_t)n * 192;
#pragma unroll
        for (int i4 = 0; i4 < 16; ++i4) {
            ub16x4 hh, mm, ll;
#pragma unroll
            for (int i = 0; i < 4; ++i) {
                float x = h3[i4 * 4 + i];
                unsigned short hb = bf16rne(x);  float fh = bf16tof(hb);
                float r1 = x - fh;
                unsigned short mb = bf16rne(r1); float fm = bf16tof(mb);
                float r2 = r1 - fm;
                unsigned short lb = bf16rne(r2);
                hh[i] = hb; mm[i] = mb; ll[i] = lb;
            }
            *(ub16x4*)(xi + rb +       i4 * 4) = hh;
            *(ub16x4*)(xi + rb +  64 + i4 * 4) = mm;
            *(ub16x4*)(xi + rb + 128 + i4 * 4) = ll;
        }
    }
}

// ---------------------------------------------------------------------------
// K3: exact-set kNN in 64-dim feature space via bf16x3 split-MFMA.
// v14 = v11's kernel verbatim (370 us, VGPR 64, WRITE 44 MB, Occ 36%).
// v12/v13's register prefetch experiment is DEAD: the allocator targets the
// 8-wave/SIMD 64-VGPR budget regardless of launch_bounds(256,4) or
// amdgpu_waves_per_eu(4,4), spilling the prefetch window to scratch
// (WRITE 44->366 MB both times). In-loop loads it is.
// Structure: 40960 B LDS exactly -> 4 blocks/CU, zero tail; per-tile
// lockstep barrier (L2-resident candidate stream, FETCH 15 MB); XOR-swizzled
// wave-private dist stripes; (b,s)-in-low-bits decode. absmax 0.0.
__global__ __launch_bounds__(256, 4) void k_knn64(const unsigned short* __restrict__ xi,
                                                  const float* __restrict__ d2x1,
                                                  float* __restrict__ partD, int* __restrict__ partI)
{
    __shared__ bf16x8 qlds[1536];       // 24576 B: [pl][qb][kc][lane]
    __shared__ float dlds[4 * 16 * 64]; // 16384 B: per-wave swizzled stripes
    // total 40960 B exactly -> 4 blocks/CU

    int t = threadIdx.x;
    int blk = blockIdx.x;
    int qt = blk >> 4;                  // (b,s) in low 4 bits
    int bb = (blk >> 1) & 7;
    int s  = blk & 1;
    int qbase  = bb * 4096 + qt * 64;
    int cstart = s * 2048;
    int w = t >> 6, l = t & 63;
    int r16 = l & 15, g = l >> 4;

    // stage Q fragments once (block-shared; same lane-pattern for all waves)
    for (int f = t; f < 1536; f += 256) {
        int lane = f & 63, kc = (f >> 6) & 1, qb = (f >> 7) & 3, pl = f >> 9;
        size_t off = ((size_t)(qbase + qb * 16 + (lane & 15))) * 192 + pl * 64
                   + kc * 32 + 8 * (lane >> 4);
        qlds[f] = *(const bf16x8*)(xi + off);
    }
    float d2ql = d2x1[qbase + l];
    __syncthreads();

    float bd[20]; int bi[20];
#pragma unroll
    for (int j = 0; j < 20; ++j) { bd[j] = F_INF; bi[j] = -1; }
    int cnt = 0; float thr = F_INF;
    float a0 = 0, a1 = 0, a2 = 0, a3 = 0;
    int   j0 = 0, j1 = 0, j2 = 0, j3 = 0;

    const bf16x8* qf = qlds;            // idx: ((pl*4+qb)*2+kc)*64 + l
    float* myD = dlds + w * 1024;       // wave-private 16x64 swizzled stripe

    for (int T = 0; T < 32; ++T) {
        __syncthreads();                // per-tile lockstep (v10's L2 fix)
        int csl = cstart + T * 64 + 16 * w;     // batch-local stripe base
        int csg = bb * 4096 + csl;

        bf16x8 bh[2], bm[2], blv[2];
#pragma unroll
        for (int kc = 0; kc < 2; ++kc) {
            size_t rb = ((size_t)(csg + r16)) * 192 + kc * 32 + 8 * g;
            bh[kc]  = *(const bf16x8*)(xi + rb);
            bm[kc]  = *(const bf16x8*)(xi + rb + 64);
            blv[kc] = *(const bf16x8*)(xi + rb + 128);
        }
        float d2cv = (l < 16) ? d2x1[csg + l] : 0.f;

        floatx4 acc[4];
#pragma unroll
        for (int qb = 0; qb < 4; ++qb) acc[qb] = (floatx4){0.f, 0.f, 0.f, 0.f};
#pragma unroll
        for (int qb = 0; qb < 4; ++qb)
#pragma unroll
            for (int kc = 0; kc < 2; ++kc) {
                bf16x8 qh_ = qf[((0 * 4 + qb) * 2 + kc) * 64 + l];
                bf16x8 qm_ = qf[((1 * 4 + qb) * 2 + kc) * 64 + l];
                bf16x8 ql_ = qf[((2 * 4 + qb) * 2 + kc) * 64 + l];
                acc[qb] = __builtin_amdgcn_mfma_f32_16x16x32_bf16(qh_, bh[kc],  acc[qb], 0, 0, 0);
                acc[qb] = __builtin_amdgcn_mfma_f32_16x16x32_bf16(qh_, bm[kc],  acc[qb], 0, 0, 0);
                acc[qb] = __builtin_amdgcn_mfma_f32_16x16x32_bf16(qm_, bh[kc],  acc[qb], 0, 0, 0);
                acc[qb] = __builtin_amdgcn_mfma_f32_16x16x32_bf16(qm_, bm[kc],  acc[qb], 0, 0, 0);
                acc[qb] = __builtin_amdgcn_mfma_f32_16x16x32_bf16(qh_, blv[kc], acc[qb], 0, 0, 0);
                acc[qb] = __builtin_amdgcn_mfma_f32_16x16x32_bf16(ql_, bh[kc],  acc[qb], 0, 0, 0);
            }

        // dots -> wave-private stripe: d[cand r16][query], col-swizzled
        // (perm = (r16&7)<<2, bits 2-4: float4 block stays contiguous).
#pragma unroll
        for (int qb = 0; qb < 4; ++qb) {
            int colp = (qb * 16 + g * 4) ^ ((r16 & 7) << 2);
            *(floatx4*)&myD[r16 * 64 + colp] = acc[qb];
        }

        // append: lane l = query l, cands c ascending (exact list order)
#pragma unroll
        for (int c = 0; c < 16; ++c) {
            float dot = myD[c * 64 + (l ^ ((c & 7) << 2))];
            float d2c = __shfl(d2cv, c);
            float dist = (d2ql + d2c) - 2.0f * dot;
            APPEND(dist, csl + c);
        }
    }
    FLUSH();

    size_t base = (((size_t)(s * 4 + w)) * 32768 + (qbase + l)) * 20;
#pragma unroll
    for (int k = 0; k < 20; ++k) { partD[base + k] = bd[k]; partI[base + k] = bi[k]; }
}

// ---------------------------------------------------------------------------
// K4a: EdgeConv-2 full decomposition. T = x1@(Wa-Wb)+b, V = x1@Wb.
__global__ __launch_bounds__(128) void k_prep2(const float* __restrict__ x1, const float* __restrict__ w,
                                               const float* __restrict__ bias,
                                               float* __restrict__ T, float* __restrict__ V)
{
    __shared__ float xs[8][64];
    int o = threadIdx.x;
    int g = blockIdx.x * 8;
    for (int t = threadIdx.x; t < 512; t += 128) xs[t >> 6][t & 63] = x1[(size_t)g * 64 + t];
    __syncthreads();
    float at[8] = {}, av[8] = {};
    for (int i = 0; i < 64; ++i) {
        float wt = w[i * 128 + o], wv = w[(64 + i) * 128 + o];
#pragma unroll
        for (int p = 0; p < 8; ++p) {
            float xv = xs[p][i];
            at[p] = fmaf(xv, wt, at[p]);
            av[p] = fmaf(xv, wv, av[p]);
        }
    }
    float bo = bias[o];
#pragma unroll
    for (int p = 0; p < 8; ++p) {
        T[(size_t)(g + p) * 128 + o] = at[p] - av[p] + bo;
        V[(size_t)(g + p) * 128 + o] = av[p];
    }
}

// K4b: x2[n] = T[n] + max_k V[idx2[n,k]]
__global__ __launch_bounds__(256) void k_edge2(const float* __restrict__ T, const float* __restrict__ V,
                                               const int* __restrict__ idx2, float* __restrict__ x2)
{
    int t = threadIdx.x;
    int p = t >> 5, oc = t & 31;
    int n = blockIdx.x * 8 + p;
    int b = n >> 12;
    const int* ip = idx2 + (size_t)n * 20;
    float4 mx = make_float4(-F_INF, -F_INF, -F_INF, -F_INF);
    for (int k = 0; k < 20; ++k) {
        int j = ip[k];
        float4 v = ((const float4*)(V + ((size_t)(b * 4096) + j) * 128))[oc];
        mx.x = fmaxf(mx.x, v.x); mx.y = fmaxf(mx.y, v.y);
        mx.z = fmaxf(mx.z, v.z); mx.w = fmaxf(mx.w, v.w);
    }
    float4 tv = ((const float4*)(T + (size_t)n * 128))[oc];
    float4 r = make_float4(tv.x + mx.x, tv.y + mx.y, tv.z + mx.z, tv.w + mx.w);
    ((float4*)(x2 + (size_t)n * 128))[oc] = r;
}

// ---------------------------------------------------------------------------
// K5: out = max_n( [x1|x2] @ lin1_w + b ), partial max over 32-point chunks.
__global__ __launch_bounds__(256) void k_lin1max(const float* __restrict__ x1, const float* __restrict__ x2,
                                                 const float* __restrict__ w, const float* __restrict__ bias,
                                                 float* __restrict__ partial)
{
    __shared__ float fs[32][192];
    int blk = blockIdx.x;                 // 0..1023
    int b = blk >> 7, c = blk & 127;
    int base_n = b * 4096 + c * 32;
    for (int t = threadIdx.x; t < 2048; t += 256) {
        int n = t >> 6, i = t & 63;
        fs[n][i] = x1[(size_t)(base_n + n) * 64 + i];
    }
    for (int t = threadIdx.x; t < 4096; t += 256) {
        int n = t >> 7, i = t & 127;
        fs[n][64 + i] = x2[(size_t)(base_n + n) * 128 + i];
    }
    __syncthreads();

    float acc[32][4];
#pragma unroll
    for (int n = 0; n < 32; ++n)
#pragma unroll
        for (int oo = 0; oo < 4; ++oo) acc[n][oo] = 0.f;

    for (int i4 = 0; i4 < 48; ++i4) {
        float wv[4][4];
#pragma unroll
        for (int r = 0; r < 4; ++r)
#pragma unroll
            for (int oo = 0; oo < 4; ++oo)
                wv[r][oo] = w[(size_t)(i4 * 4 + r) * 1024 + oo * 256 + threadIdx.x];
#pragma unroll
        for (int n = 0; n < 32; ++n) {
            float4 f = *(const float4*)&fs[n][i4 * 4];
#pragma unroll
            for (int oo = 0; oo < 4; ++oo) {
                acc[n][oo] = fmaf(f.x, wv[0][oo], acc[n][oo]);
                acc[n][oo] = fmaf(f.y, wv[1][oo], acc[n][oo]);
                acc[n][oo] = fmaf(f.z, wv[2][oo], acc[n][oo]);
                acc[n][oo] = fmaf(f.w, wv[3][oo], acc[n][oo]);
            }
        }
    }
#pragma unroll
    for (int oo = 0; oo < 4; ++oo) {
        int o = oo * 256 + threadIdx.x;
        float m = -F_INF;
#pragma unroll
        for (int n = 0; n < 32; ++n) m = fmaxf(m, acc[n][oo]);
        partial[((size_t)b * 128 + c) * 1024 + o] = m + bias[o];
    }
}

__global__ void k_red(const float* __restrict__ partial, float* __restrict__ pooled)
{
    int t = blockIdx.x * 256 + threadIdx.x;  // 8192
    int b = t >> 10, o = t & 1023;
    float m = -F_INF;
    for (int c = 0; c < 128; ++c) m = fmaxf(m, partial[((size_t)b * 128 + c) * 1024 + o]);
    pooled[t] = m;
}

// ---------------------------------------------------------------------------
// classifier head
__global__ __launch_bounds__(256) void k_fc1(const float* __restrict__ pooled, const float* __restrict__ w,
                                             const float* __restrict__ bias, float* __restrict__ g1)
{
    __shared__ float ps[8 * 1024];
    for (int t = threadIdx.x; t < 8192; t += 256) ps[t] = pooled[t];
    __syncthreads();
    int o = blockIdx.x * 256 + threadIdx.x;   // 0..511
    float acc[8] = {};
    for (int i4 = 0; i4 < 256; ++i4) {
        float w0 = w[(size_t)(i4 * 4 + 0) * 512 + o];
        float w1v = w[(size_t)(i4 * 4 + 1) * 512 + o];
        float w2v = w[(size_t)(i4 * 4 + 2) * 512 + o];
        float w3v = w[(size_t)(i4 * 4 + 3) * 512 + o];
#pragma unroll
        for (int bb = 0; bb < 8; ++bb) {
            float4 f = *(const float4*)&ps[bb * 1024 + i4 * 4];
            acc[bb] = fmaf(f.x, w0, fmaf(f.y, w1v, fmaf(f.z, w2v, fmaf(f.w, w3v, acc[bb]))));
        }
    }
    float bo = bias[o];
#pragma unroll
    for (int bb = 0; bb < 8; ++bb) g1[bb * 512 + o] = fmaxf(acc[bb] + bo, 0.f);
}

__global__ __launch_bounds__(256) void k_fc2(const float* __restrict__ g1, const float* __restrict__ w,
                                             const float* __restrict__ bias, float* __restrict__ g2)
{
    __shared__ float gs[8 * 512];
    for (int t = threadIdx.x; t < 4096; t += 256) gs[t] = g1[t];
    __syncthreads();
    int o = threadIdx.x;                      // 0..255
    float acc[8] = {};
    for (int i4 = 0; i4 < 128; ++i4) {
        float w0 = w[(size_t)(i4 * 4 + 0) * 256 + o];
        float w1v = w[(size_t)(i4 * 4 + 1) * 256 + o];
        float w2v = w[(size_t)(i4 * 4 + 2) * 256 + o];
        float w3v = w[(size_t)(i4 * 4 + 3) * 256 + o];
#pragma unroll
        for (int bb = 0; bb < 8; ++bb) {
            float4 f = *(const float4*)&gs[bb * 512 + i4 * 4];
            acc[bb] = fmaf(f.x, w0, fmaf(f.y, w1v, fmaf(f.z, w2v, fmaf(f.w, w3v, acc[bb]))));
        }
    }
    float bo = bias[o];
#pragma unroll
    for (int bb = 0; bb < 8; ++bb) g2[bb * 256 + o] = fmaxf(acc[bb] + bo, 0.f);
}

__global__ void k_fc3sm(const float* __restrict__ g2, const float* __restrict__ w,
                        const float* __restrict__ bias, float* __restrict__ out)
{
    int t = threadIdx.x;      // 128 = 8 batches x 16 lanes
    int b = t >> 4, l = t & 15;
    float lg = -F_INF;
    if (l < 10) {
        float a = bias[l];
        for (int i = 0; i < 256; ++i) a = fmaf(g2[b * 256 + i], w[i * 10 + l], a);
        lg = a;
    }
    float m = lg;
    m = fmaxf(m, __shfl_xor(m, 1, 16));
    m = fmaxf(m, __shfl_xor(m, 2, 16));
    m = fmaxf(m, __shfl_xor(m, 4, 16));
    m = fmaxf(m, __shfl_xor(m, 8, 16));
    float e = (l < 10) ? expf(lg - m) : 0.f;
    float s = e;
    s += __shfl_xor(s, 1, 16);
    s += __shfl_xor(s, 2, 16);
    s += __shfl_xor(s, 4, 16);
    s += __shfl_xor(s, 8, 16);
    if (l < 10) out[b * 10 + l] = (lg - m) - logf(s);
}

// ---------------------------------------------------------------------------
extern "C" void kernel_launch(void* const* d_in, const int* in_sizes, int n_in,
                              void* d_out, int out_size, void* d_ws, size_t ws_size,
                              hipStream_t stream)
{
    (void)in_sizes; (void)n_in; (void)out_size; (void)ws_size;
    const float* data  = (const float*)d_in[0];
    const float* c1w1  = (const float*)d_in[1];
    const float* c1b1  = (const float*)d_in[2];
    const float* c1w2  = (const float*)d_in[3];
    const float* c1b2  = (const float*)d_in[4];
    const float* c1w3  = (const float*)d_in[5];
    const float* c1b3  = (const float*)d_in[6];
    const float* c2w1  = (const float*)d_in[7];
    const float* c2b1  = (const float*)d_in[8];
    const float* lin1w = (const float*)d_in[9];
    const float* lin1b = (const float*)d_in[10];
    const float* mw1   = (const float*)d_in[11];
    const float* mb1   = (const float*)d_in[12];
    const float* mw2   = (const float*)d_in[13];
    const float* mb2   = (const float*)d_in[14];
    const float* mw3   = (const float*)d_in[15];
    const float* mb3   = (const float*)d_in[16];
    float* ws  = (float*)d_ws;
    int*   wsi = (int*)d_ws;
    float* out = (float*)d_out;

    const size_t OFF_IDX1 = 0;          // 655360 i
    const size_t OFF_IDX2 = 0;          // 655360 i (IDX1 dead by then)
    const size_t OFF_X1   = 655360;     // 2097152 f
    const size_t OFF_D2   = 2752512;    // 32768 f
    const size_t OFF_PM   = 2785280;    // 2097152 f
    const size_t OFF_Q    = 4882432;    // 2097152 f
    const size_t OFF_PD   = 2785280;    // 5242880 f   (knn phases)
    const size_t OFF_PI   = 8028160;    // 5242880 i
    const size_t OFF_T    = 2785280;    // 4194304 f
    const size_t OFF_V    = 6979584;    // 4194304 f
    const size_t OFF_X2   = 11173888;   // 4194304 f
    const size_t OFF_PART = 15368192;   // 1048576 f
    const size_t OFF_POOL = 16416768;   // 8192 f
    const size_t OFF_G1   = 16424960;   // 4096 f
    const size_t OFF_G2   = 16429056;   // 2048 f
    // interleaved bf16x3 plane xi[32768][192]: 6291456 ushorts = 3145728
    // float-slots at [13271040, 16416768) — live from k_edge1 until the 2nd
    // k_merge8; X2/PART are dead during that window.
    const size_t OFF_XI   = 13271040;

    k_knn2d<<<1024, 256, 0, stream>>>(data, ws + OFF_PD, wsi + OFF_PI);
    k_merge8<<<512, 64, 0, stream>>>(ws + OFF_PD, wsi + OFF_PI, wsi + OFF_IDX1);
    k_prep1<<<8192, 256, 0, stream>>>(data, c1w1, c1b1, ws + OFF_PM, ws + OFF_Q);
    k_edge1<<<2731, 256, 0, stream>>>(ws + OFF_PM, ws + OFF_Q, wsi + OFF_IDX1,
                                      c1w2, c1b2, c1w3, c1b3, ws + OFF_X1, ws + OFF_D2,
                                      (unsigned short*)(ws + OFF_XI));
    k_knn64<<<1024, 256, 0, stream>>>((const unsigned short*)(ws + OFF_XI),
                                      ws + OFF_D2, ws + OFF_PD, wsi + OFF_PI);
    k_merge8<<<512, 64, 0, stream>>>(ws + OFF_PD, wsi + OFF_PI, wsi + OFF_IDX2);
    k_prep2<<<4096, 128, 0, stream>>>(ws + OFF_X1, c2w1, c2b1, ws + OFF_T, ws + OFF_V);
    k_edge2<<<4096, 256, 0, stream>>>(ws + OFF_T, ws + OFF_V, wsi + OFF_IDX2, ws + OFF_X2);
    k_lin1max<<<1024, 256, 0, stream>>>(ws + OFF_X1, ws + OFF_X2, lin1w, lin1b, ws + OFF_PART);
    k_red<<<32, 256, 0, stream>>>(ws + OFF_PART, ws + OFF_POOL);
    k_fc1<<<2, 256, 0, stream>>>(ws + OFF_POOL, mw1, mb1, ws + OFF_G1);
    k_fc2<<<1, 256, 0, stream>>>(ws + OFF_G1, mw2, mb2, ws + OFF_G2);
    k_fc3sm<<<1, 128, 0, stream>>>(ws + OFF_G2, mw3, mb3, out);
}

// Round 14
// 1375.788 us; speedup vs baseline: 1.0812x; 1.0294x over previous
//
#include <hip/hip_runtime.h>
#include <math.h>

#define DEVI static __device__ __forceinline__
#define F_INF __builtin_inff()

typedef short bf16x8 __attribute__((ext_vector_type(8)));    // 8 bf16 = 4 VGPR
typedef float floatx4 __attribute__((ext_vector_type(4)));   // MFMA acc
typedef unsigned short ub16x4 __attribute__((ext_vector_type(4)));

// bf16 round-to-nearest-even helpers (finite data only)
DEVI unsigned short bf16rne(float f)
{
    unsigned u = __float_as_uint(f);
    unsigned r = (u + 0x7FFFu + ((u >> 16) & 1u)) >> 16;
    return (unsigned short)r;
}
DEVI float bf16tof(unsigned short h) { return __uint_as_float(((unsigned)h) << 16); }

// ---------------------------------------------------------------------------
// Exactness scheme for kNN top-20 (set semantics — idx feeds max-pools only):
//  * each of 8 lists per query scans a disjoint candidate range in ASCENDING
//    index order, sorted top-20 with plain strict-< insertion,
//  * k_merge8 does a full (d, idx)-lexicographic tournament over the 8 lists
//    -> global top-20 set == jax.lax.top_k's set (list order irrelevant).
// bf16x3 split-MFMA dot (hh+hm+mh+mm+hl+lh): error ~2^-24 relative — verified
// absmax 0.0 end-to-end in v7-v14.
DEVI bool lexlt(float d, int i, float dr, int ir)
{
    return (d < dr) || (d == dr && i < ir);
}

// plain-< sorted insertion; (INF, any) is a guaranteed no-op.
DEVI void insert20(float* bd, int* bi, float d, int i)
{
#pragma unroll
    for (int j = 19; j >= 1; --j) {
        bool lt  = d < bd[j];
        bool ltp = d < bd[j - 1];
        float nd = ltp ? bd[j - 1] : d;
        int   ni = ltp ? bi[j - 1] : i;
        bd[j] = lt ? nd : bd[j];
        bi[j] = lt ? ni : bi[j];
    }
    bool lt0 = d < bd[0];
    bd[0] = lt0 ? d : bd[0];
    bi[0] = lt0 ? i : bi[0];
}

DEVI void insert_tiered(float* bd, int* bi, float d, int i)
{
    if (__all(!(d < bd[15]))) {
#pragma unroll
        for (int j = 19; j >= 17; --j) {
            bool lt  = d < bd[j];
            bool ltp = d < bd[j - 1];
            float nd = ltp ? bd[j - 1] : d;
            int   ni = ltp ? bi[j - 1] : i;
            bd[j] = lt ? nd : bd[j];
            bi[j] = lt ? ni : bi[j];
        }
        bool lt16 = d < bd[16];
        bd[16] = lt16 ? d : bd[16];
        bi[16] = lt16 ? i : bi[16];
    } else if (__all(!(d < bd[7]))) {
#pragma unroll
        for (int j = 19; j >= 9; --j) {
            bool lt  = d < bd[j];
            bool ltp = d < bd[j - 1];
            float nd = ltp ? bd[j - 1] : d;
            int   ni = ltp ? bi[j - 1] : i;
            bd[j] = lt ? nd : bd[j];
            bi[j] = lt ? ni : bi[j];
        }
        bool lt8 = d < bd[8];
        bd[8] = lt8 ? d : bd[8];
        bi[8] = lt8 ? i : bi[8];
    } else {
        insert20(bd, bi, d, i);
    }
}

DEVI void flushT(float* bd, int* bi, float d, int i, int e, int cnt)
{
    bool want = (e < cnt) && (d < bd[19]);
    if (__any(want))
        insert_tiered(bd, bi, want ? d : F_INF, want ? i : 0x7FFFFFFF);
}

// register append-buffer (cap 4) + wave-coupled flush
#define FLUSH() do { \
    flushT(bd, bi, a0, j0, 0, cnt); \
    flushT(bd, bi, a1, j1, 1, cnt); \
    flushT(bd, bi, a2, j2, 2, cnt); \
    flushT(bd, bi, a3, j3, 3, cnt); \
    cnt = 0; thr = bd[19]; \
} while (0)

#define APPEND(dv, civ) do { \
    bool pass_ = (dv) < thr; \
    if (pass_) { \
        a0 = (cnt == 0) ? (dv) : a0; j0 = (cnt == 0) ? (civ) : j0; \
        a1 = (cnt == 1) ? (dv) : a1; j1 = (cnt == 1) ? (civ) : j1; \
        a2 = (cnt == 2) ? (dv) : a2; j2 = (cnt == 2) ? (civ) : j2; \
        a3 = (cnt == 3) ? (dv) : a3; j3 = (cnt == 3) ? (civ) : j3; \
        ++cnt; \
    } \
    if (__any(cnt == 4)) { FLUSH(); } \
} while (0)

// ---------------------------------------------------------------------------
// K-merge: exact 8-way lex tournament. LIST-MAJOR layout —
// partD/partI[(list*32768 + q)*20 + p], list stride LS = 655360.
__global__ __launch_bounds__(64) void k_merge8(const float* __restrict__ partD,
                                               const int* __restrict__ partI,
                                               int* __restrict__ idxo)
{
    const size_t LS = 655360;           // 32768 * 20
    int q = blockIdx.x * 64 + threadIdx.x;
    const float* rd = partD + (size_t)q * 20;
    const int*   ri = partI + (size_t)q * 20;
    int p0 = 0, p1 = 0, p2 = 0, p3 = 0, p4 = 0, p5 = 0, p6 = 0, p7 = 0;
    int* op = idxo + (size_t)q * 20;
    for (int r = 0; r < 20; ++r) {      // p <= r < 20 at read time: never OOB
        float d0 = rd[p0],            d1 = rd[LS + p1];
        float d2v = rd[2 * LS + p2],  d3 = rd[3 * LS + p3];
        float d4 = rd[4 * LS + p4],   d5 = rd[5 * LS + p5];
        float d6 = rd[6 * LS + p6],   d7 = rd[7 * LS + p7];
        int   i0 = ri[p0],            i1 = ri[LS + p1];
        int   i2 = ri[2 * LS + p2],   i3 = ri[3 * LS + p3];
        int   i4v = ri[4 * LS + p4],  i5 = ri[5 * LS + p5];
        int   i6 = ri[6 * LS + p6],   i7 = ri[7 * LS + p7];
        bool wA = lexlt(d1, i1, d0, i0);   float dA = wA ? d1 : d0; int iA = wA ? i1 : i0; int sA = wA ? 1 : 0;
        bool wB = lexlt(d3, i3, d2v, i2);  float dB = wB ? d3 : d2v; int iB = wB ? i3 : i2; int sB = wB ? 3 : 2;
        bool wC = lexlt(d5, i5, d4, i4v);  float dC = wC ? d5 : d4; int iC = wC ? i5 : i4v; int sC = wC ? 5 : 4;
        bool wD = lexlt(d7, i7, d6, i6);   float dD = wD ? d7 : d6; int iD = wD ? i7 : i6; int sD = wD ? 7 : 6;
        bool wE = lexlt(dB, iB, dA, iA);   float dE = wE ? dB : dA; int iE = wE ? iB : iA; int sE = wE ? sB : sA;
        bool wF = lexlt(dD, iD, dC, iC);   float dF = wF ? dD : dC; int iF = wF ? iD : iC; int sF = wF ? sD : sC;
        bool wG = lexlt(dF, iF, dE, iE);   int ig = wG ? iF : iE;   int sg = wG ? sF : sE;
        op[r] = ig;
        p0 += (sg == 0); p1 += (sg == 1); p2 += (sg == 2); p3 += (sg == 3);
        p4 += (sg == 4); p5 += (sg == 5); p6 += (sg == 6); p7 += (sg == 7);
    }
}

// ---------------------------------------------------------------------------
// K1: exact kNN on 2D points. 1024 blocks = 8 b x 64 qtile x 2 split.
// list-major part writes.
__global__ __launch_bounds__(256, 4) void k_knn2d(const float* __restrict__ x,
                                                  float* __restrict__ partD, int* __restrict__ partI)
{
    __shared__ float2 pts[4096];
    int t = threadIdx.x;
    int blk = blockIdx.x;
    int b = blk >> 7;
    int qt = (blk >> 1) & 63;
    int s = blk & 1;
    const float* xb = x + (size_t)b * 4096 * 2;
    for (int f = t; f < 2048; f += 256)
        ((float4*)pts)[f] = ((const float4*)xb)[f];
    __syncthreads();

    int l = t & 63, w = t >> 6;
    int q = qt * 64 + l;
    float2 qp = pts[q];
    float d2i = qp.x * qp.x + qp.y * qp.y;

    float bd[20]; int bi[20];
#pragma unroll
    for (int j = 0; j < 20; ++j) { bd[j] = F_INF; bi[j] = -1; }
    int cnt = 0; float thr = F_INF;
    float a0 = 0, a1 = 0, a2 = 0, a3 = 0;
    int   j0 = 0, j1 = 0, j2 = 0, j3 = 0;

    int m0 = s * 2048 + w * 512;
    for (int m = m0; m < m0 + 512; ++m) {
        float2 p = pts[m];                       // wave-uniform -> broadcast
        float d2j = p.x * p.x + p.y * p.y;
        float dot = qp.x * p.x + qp.y * p.y;
        float dist = (d2i + d2j) - 2.0f * dot;
        APPEND(dist, m);
    }
    FLUSH();

    size_t base = (((size_t)(s * 4 + w)) * 32768 + (b * 4096 + q)) * 20;
#pragma unroll
    for (int k = 0; k < 20; ++k) { partD[base + k] = bd[k]; partI[base + k] = bi[k]; }
}

// ---------------------------------------------------------------------------
// K2a: per-point layer-1 decomposition.
__global__ void k_prep1(const float* __restrict__ x, const float* __restrict__ w1,
                        const float* __restrict__ b1, float* __restrict__ pm, float* __restrict__ qv)
{
    int tid = blockIdx.x * 256 + threadIdx.x;   // 8*4096*64
    int n = tid >> 6, i = tid & 63;
    float x0 = x[(size_t)n * 2], x1v = x[(size_t)n * 2 + 1];
    float wa = w1[i], wb = w1[64 + i], wc = w1[128 + i], wd = w1[192 + i];
    pm[tid] = fmaf(x0, wa - wc, fmaf(x1v, wb - wd, b1[i]));
    qv[tid] = fmaf(x0, wc, x1v * wd);
}

// ---------------------------------------------------------------------------
// K2: EdgeConv-1 main. 20-lane groups, segmented shuffle max.
// (v15: fused split REVERTED — the k==0 divergent convert/store tail cost
// ~65 us in k_edge1 vs ~30 us for the standalone coalesced k_split.)
__global__ __launch_bounds__(256) void k_edge1(const float* __restrict__ pm, const float* __restrict__ q,
                                               const int* __restrict__ idx1,
                                               const float* __restrict__ w2, const float* __restrict__ b2,
                                               const float* __restrict__ w3, const float* __restrict__ b3,
                                               float* __restrict__ x1, float* __restrict__ d2x1)
{
    int t = threadIdx.x;
    int w = t >> 6, l = t & 63;
    int pg = l / 20;                 // group in wave (3 = idle lanes 60..63)
    int k  = l - pg * 20;
    int n0 = blockIdx.x * 12 + w * 3 + pg;
    bool valid = (l < 60) && (n0 < 32768);
    int n = valid ? n0 : 0;
    int b = n >> 12;
    int j = idx1[(size_t)n * 20 + k];
    const float4* pmr = (const float4*)(pm + (size_t)n * 64);
    const float4* qr  = (const float4*)(q + ((size_t)(b * 4096) + j) * 64);

    float h1[64];
#pragma unroll
    for (int i4 = 0; i4 < 16; ++i4) {
        float4 a = pmr[i4], c = qr[i4];
        h1[i4 * 4 + 0] = fmaxf(a.x + c.x, 0.f);
        h1[i4 * 4 + 1] = fmaxf(a.y + c.y, 0.f);
        h1[i4 * 4 + 2] = fmaxf(a.z + c.z, 0.f);
        h1[i4 * 4 + 3] = fmaxf(a.w + c.w, 0.f);
    }
    float h2[64];
#pragma unroll
    for (int o = 0; o < 64; ++o) h2[o] = b2[o];
#pragma unroll
    for (int i = 0; i < 64; ++i) {
        const float* r = w2 + i * 64;       // wave-uniform -> scalar loads
#pragma unroll
        for (int o = 0; o < 64; ++o) h2[o] = fmaf(h1[i], r[o], h2[o]);
    }
#pragma unroll
    for (int o = 0; o < 64; ++o) h2[o] = fmaxf(h2[o], 0.f);

    float h3[64];
#pragma unroll
    for (int o = 0; o < 64; ++o) h3[o] = b3[o];
#pragma unroll
    for (int i = 0; i < 64; ++i) {
        const float* r = w3 + i * 64;
#pragma unroll
        for (int o = 0; o < 64; ++o) h3[o] = fmaf(h2[i], r[o], h3[o]);
    }

    // segmented max over the 20-lane group
    int s16 = (k + 16 < 20) ? (l + 16) : l;
    int s8  = (k + 8  < 20) ? (l + 8)  : l;
    int s4  = (k + 4  < 20) ? (l + 4)  : l;
    int s2  = (k + 2  < 20) ? (l + 2)  : l;
    int s1  = (k + 1  < 20) ? (l + 1)  : l;
#pragma unroll
    for (int o = 0; o < 64; ++o) {
        float v = h3[o];
        v = fmaxf(v, __shfl(v, s16));
        v = fmaxf(v, __shfl(v, s8));
        v = fmaxf(v, __shfl(v, s4));
        v = fmaxf(v, __shfl(v, s2));
        v = fmaxf(v, __shfl(v, s1));
        h3[o] = v;
    }
    if (valid && k == 0) {
        float d2 = 0.f;
#pragma unroll
        for (int o = 0; o < 64; ++o) d2 += h3[o] * h3[o];
        float4* op = (float4*)(x1 + (size_t)n * 64);
#pragma unroll
        for (int i4 = 0; i4 < 16; ++i4)
            op[i4] = make_float4(h3[i4 * 4], h3[i4 * 4 + 1], h3[i4 * 4 + 2], h3[i4 * 4 + 3]);
        d2x1[n] = d2;
    }
}

// ---------------------------------------------------------------------------
// K2b: bf16x3 split of x1, INTERLEAVED layout xi[row][3][64] (384 B rows) —
// single stream, no 4 MiB L2 set-aliasing between planes.
__global__ __launch_bounds__(256) void k_split(const float* __restrict__ x1,
                                               unsigned short* __restrict__ xi)
{
    int id = blockIdx.x * 256 + threadIdx.x;    // 0..524287
    int n = id >> 4, dp = id & 15;              // row, dim-quad
    float4 v = ((const float4*)x1)[id];
    float vv[4] = { v.x, v.y, v.z, v.w };
    ub16x4 h, m, l;
#pragma unroll
    for (int i = 0; i < 4; ++i) {
        float x = vv[i];
        unsigned short hb = bf16rne(x);  float fh = bf16tof(hb);
        float r1 = x - fh;                       // exact
        unsigned short mb = bf16rne(r1); float fm = bf16tof(mb);
        float r2 = r1 - fm;                      // exact
        unsigned short lb = bf16rne(r2);
        h[i] = hb; m[i] = mb; l[i] = lb;
    }
    size_t rb = (size_t)n * 192;
    *(ub16x4*)(xi + rb +       dp * 4) = h;
    *(ub16x4*)(xi + rb +  64 + dp * 4) = m;
    *(ub16x4*)(xi + rb + 128 + dp * 4) = l;
}

// ---------------------------------------------------------------------------
// K3: exact-set kNN in 64-dim feature space via bf16x3 split-MFMA.
// Final form (v11): 40960 B LDS exactly -> 4 blocks/CU, zero tail; per-tile
// lockstep barrier (L2-resident candidate stream, FETCH 15 MB); XOR-swizzled
// wave-private dist stripes; (b,s)-in-low-bits decode; d2c via lane shuffle.
// Register-prefetch pipelining is compiler-blocked (v12/v13: allocator keeps
// the 64-VGPR 8-wave target and spills). Measured 370 us, absmax 0.0.
__global__ __launch_bounds__(256, 4) void k_knn64(const unsigned short* __restrict__ xi,
                                                  const float* __restrict__ d2x1,
                                                  float* __restrict__ partD, int* __restrict__ partI)
{
    __shared__ bf16x8 qlds[1536];       // 24576 B: [pl][qb][kc][lane]
    __shared__ float dlds[4 * 16 * 64]; // 16384 B: per-wave swizzled stripes
    // total 40960 B exactly -> 4 blocks/CU

    int t = threadIdx.x;
    int blk = blockIdx.x;
    int qt = blk >> 4;                  // (b,s) in low 4 bits
    int bb = (blk >> 1) & 7;
    int s  = blk & 1;
    int qbase  = bb * 4096 + qt * 64;
    int cstart = s * 2048;
    int w = t >> 6, l = t & 63;
    int r16 = l & 15, g = l >> 4;

    // stage Q fragments once (block-shared; same lane-pattern for all waves)
    for (int f = t; f < 1536; f += 256) {
        int lane = f & 63, kc = (f >> 6) & 1, qb = (f >> 7) & 3, pl = f >> 9;
        size_t off = ((size_t)(qbase + qb * 16 + (lane & 15))) * 192 + pl * 64
                   + kc * 32 + 8 * (lane >> 4);
        qlds[f] = *(const bf16x8*)(xi + off);
    }
    float d2ql = d2x1[qbase + l];
    __syncthreads();

    float bd[20]; int bi[20];
#pragma unroll
    for (int j = 0; j < 20; ++j) { bd[j] = F_INF; bi[j] = -1; }
    int cnt = 0; float thr = F_INF;
    float a0 = 0, a1 = 0, a2 = 0, a3 = 0;
    int   j0 = 0, j1 = 0, j2 = 0, j3 = 0;

    const bf16x8* qf = qlds;            // idx: ((pl*4+qb)*2+kc)*64 + l
    float* myD = dlds + w * 1024;       // wave-private 16x64 swizzled stripe

    for (int T = 0; T < 32; ++T) {
        __syncthreads();                // per-tile lockstep (v10's L2 fix)
        int csl = cstart + T * 64 + 16 * w;     // batch-local stripe base
        int csg = bb * 4096 + csl;

        bf16x8 bh[2], bm[2], blv[2];
#pragma unroll
        for (int kc = 0; kc < 2; ++kc) {
            size_t rb = ((size_t)(csg + r16)) * 192 + kc * 32 + 8 * g;
            bh[kc]  = *(const bf16x8*)(xi + rb);
            bm[kc]  = *(const bf16x8*)(xi + rb + 64);
            blv[kc] = *(const bf16x8*)(xi + rb + 128);
        }
        float d2cv = (l < 16) ? d2x1[csg + l] : 0.f;

        floatx4 acc[4];
#pragma unroll
        for (int qb = 0; qb < 4; ++qb) acc[qb] = (floatx4){0.f, 0.f, 0.f, 0.f};
#pragma unroll
        for (int qb = 0; qb < 4; ++qb)
#pragma unroll
            for (int kc = 0; kc < 2; ++kc) {
                bf16x8 qh_ = qf[((0 * 4 + qb) * 2 + kc) * 64 + l];
                bf16x8 qm_ = qf[((1 * 4 + qb) * 2 + kc) * 64 + l];
                bf16x8 ql_ = qf[((2 * 4 + qb) * 2 + kc) * 64 + l];
                acc[qb] = __builtin_amdgcn_mfma_f32_16x16x32_bf16(qh_, bh[kc],  acc[qb], 0, 0, 0);
                acc[qb] = __builtin_amdgcn_mfma_f32_16x16x32_bf16(qh_, bm[kc],  acc[qb], 0, 0, 0);
                acc[qb] = __builtin_amdgcn_mfma_f32_16x16x32_bf16(qm_, bh[kc],  acc[qb], 0, 0, 0);
                acc[qb] = __builtin_amdgcn_mfma_f32_16x16x32_bf16(qm_, bm[kc],  acc[qb], 0, 0, 0);
                acc[qb] = __builtin_amdgcn_mfma_f32_16x16x32_bf16(qh_, blv[kc], acc[qb], 0, 0, 0);
                acc[qb] = __builtin_amdgcn_mfma_f32_16x16x32_bf16(ql_, bh[kc],  acc[qb], 0, 0, 0);
            }

        // dots -> wave-private stripe: d[cand r16][query], col-swizzled
        // (perm = (r16&7)<<2, bits 2-4: float4 block stays contiguous).
#pragma unroll
        for (int qb = 0; qb < 4; ++qb) {
            int colp = (qb * 16 + g * 4) ^ ((r16 & 7) << 2);
            *(floatx4*)&myD[r16 * 64 + colp] = acc[qb];
        }

        // append: lane l = query l, cands c ascending (exact list order)
#pragma unroll
        for (int c = 0; c < 16; ++c) {
            float dot = myD[c * 64 + (l ^ ((c & 7) << 2))];
            float d2c = __shfl(d2cv, c);
            float dist = (d2ql + d2c) - 2.0f * dot;
            APPEND(dist, csl + c);
        }
    }
    FLUSH();

    size_t base = (((size_t)(s * 4 + w)) * 32768 + (qbase + l)) * 20;
#pragma unroll
    for (int k = 0; k < 20; ++k) { partD[base + k] = bd[k]; partI[base + k] = bi[k]; }
}

// ---------------------------------------------------------------------------
// K4a: EdgeConv-2 full decomposition. T = x1@(Wa-Wb)+b, V = x1@Wb.
__global__ __launch_bounds__(128) void k_prep2(const float* __restrict__ x1, const float* __restrict__ w,
                                               const float* __restrict__ bias,
                                               float* __restrict__ T, float* __restrict__ V)
{
    __shared__ float xs[8][64];
    int o = threadIdx.x;
    int g = blockIdx.x * 8;
    for (int t = threadIdx.x; t < 512; t += 128) xs[t >> 6][t & 63] = x1[(size_t)g * 64 + t];
    __syncthreads();
    float at[8] = {}, av[8] = {};
    for (int i = 0; i < 64; ++i) {
        float wt = w[i * 128 + o], wv = w[(64 + i) * 128 + o];
#pragma unroll
        for (int p = 0; p < 8; ++p) {
            float xv = xs[p][i];
            at[p] = fmaf(xv, wt, at[p]);
            av[p] = fmaf(xv, wv, av[p]);
        }
    }
    float bo = bias[o];
#pragma unroll
    for (int p = 0; p < 8; ++p) {
        T[(size_t)(g + p) * 128 + o] = at[p] - av[p] + bo;
        V[(size_t)(g + p) * 128 + o] = av[p];
    }
}

// K4b: x2[n] = T[n] + max_k V[idx2[n,k]]
__global__ __launch_bounds__(256) void k_edge2(const float* __restrict__ T, const float* __restrict__ V,
                                               const int* __restrict__ idx2, float* __restrict__ x2)
{
    int t = threadIdx.x;
    int p = t >> 5, oc = t & 31;
    int n = blockIdx.x * 8 + p;
    int b = n >> 12;
    const int* ip = idx2 + (size_t)n * 20;
    float4 mx = make_float4(-F_INF, -F_INF, -F_INF, -F_INF);
    for (int k = 0; k < 20; ++k) {
        int j = ip[k];
        float4 v = ((const float4*)(V + ((size_t)(b * 4096) + j) * 128))[oc];
        mx.x = fmaxf(mx.x, v.x); mx.y = fmaxf(mx.y, v.y);
        mx.z = fmaxf(mx.z, v.z); mx.w = fmaxf(mx.w, v.w);
    }
    float4 tv = ((const float4*)(T + (size_t)n * 128))[oc];
    float4 r = make_float4(tv.x + mx.x, tv.y + mx.y, tv.z + mx.z, tv.w + mx.w);
    ((float4*)(x2 + (size_t)n * 128))[oc] = r;
}

// ---------------------------------------------------------------------------
// K5: out = max_n( [x1|x2] @ lin1_w + b ), partial max over 32-point chunks.
__global__ __launch_bounds__(256) void k_lin1max(const float* __restrict__ x1, const float* __restrict__ x2,
                                                 const float* __restrict__ w, const float* __restrict__ bias,
                                                 float* __restrict__ partial)
{
    __shared__ float fs[32][192];
    int blk = blockIdx.x;                 // 0..1023
    int b = blk >> 7, c = blk & 127;
    int base_n = b * 4096 + c * 32;
    for (int t = threadIdx.x; t < 2048; t += 256) {
        int n = t >> 6, i = t & 63;
        fs[n][i] = x1[(size_t)(base_n + n) * 64 + i];
    }
    for (int t = threadIdx.x; t < 4096; t += 256) {
        int n = t >> 7, i = t & 127;
        fs[n][64 + i] = x2[(size_t)(base_n + n) * 128 + i];
    }
    __syncthreads();

    float acc[32][4];
#pragma unroll
    for (int n = 0; n < 32; ++n)
#pragma unroll
        for (int oo = 0; oo < 4; ++oo) acc[n][oo] = 0.f;

    for (int i4 = 0; i4 < 48; ++i4) {
        float wv[4][4];
#pragma unroll
        for (int r = 0; r < 4; ++r)
#pragma unroll
            for (int oo = 0; oo < 4; ++oo)
                wv[r][oo] = w[(size_t)(i4 * 4 + r) * 1024 + oo * 256 + threadIdx.x];
#pragma unroll
        for (int n = 0; n < 32; ++n) {
            float4 f = *(const float4*)&fs[n][i4 * 4];
#pragma unroll
            for (int oo = 0; oo < 4; ++oo) {
                acc[n][oo] = fmaf(f.x, wv[0][oo], acc[n][oo]);
                acc[n][oo] = fmaf(f.y, wv[1][oo], acc[n][oo]);
                acc[n][oo] = fmaf(f.z, wv[2][oo], acc[n][oo]);
                acc[n][oo] = fmaf(f.w, wv[3][oo], acc[n][oo]);
            }
        }
    }
#pragma unroll
    for (int oo = 0; oo < 4; ++oo) {
        int o = oo * 256 + threadIdx.x;
        float m = -F_INF;
#pragma unroll
        for (int n = 0; n < 32; ++n) m = fmaxf(m, acc[n][oo]);
        partial[((size_t)b * 128 + c) * 1024 + o] = m + bias[o];
    }
}

__global__ void k_red(const float* __restrict__ partial, float* __restrict__ pooled)
{
    int t = blockIdx.x * 256 + threadIdx.x;  // 8192
    int b = t >> 10, o = t & 1023;
    float m = -F_INF;
    for (int c = 0; c < 128; ++c) m = fmaxf(m, partial[((size_t)b * 128 + c) * 1024 + o]);
    pooled[t] = m;
}

// ---------------------------------------------------------------------------
// classifier head
__global__ __launch_bounds__(256) void k_fc1(const float* __restrict__ pooled, const float* __restrict__ w,
                                             const float* __restrict__ bias, float* __restrict__ g1)
{
    __shared__ float ps[8 * 1024];
    for (int t = threadIdx.x; t < 8192; t += 256) ps[t] = pooled[t];
    __syncthreads();
    int o = blockIdx.x * 256 + threadIdx.x;   // 0..511
    float acc[8] = {};
    for (int i4 = 0; i4 < 256; ++i4) {
        float w0 = w[(size_t)(i4 * 4 + 0) * 512 + o];
        float w1v = w[(size_t)(i4 * 4 + 1) * 512 + o];
        float w2v = w[(size_t)(i4 * 4 + 2) * 512 + o];
        float w3v = w[(size_t)(i4 * 4 + 3) * 512 + o];
#pragma unroll
        for (int bb = 0; bb < 8; ++bb) {
            float4 f = *(const float4*)&ps[bb * 1024 + i4 * 4];
            acc[bb] = fmaf(f.x, w0, fmaf(f.y, w1v, fmaf(f.z, w2v, fmaf(f.w, w3v, acc[bb]))));
        }
    }
    float bo = bias[o];
#pragma unroll
    for (int bb = 0; bb < 8; ++bb) g1[bb * 512 + o] = fmaxf(acc[bb] + bo, 0.f);
}

__global__ __launch_bounds__(256) void k_fc2(const float* __restrict__ g1, const float* __restrict__ w,
                                             const float* __restrict__ bias, float* __restrict__ g2)
{
    __shared__ float gs[8 * 512];
    for (int t = threadIdx.x; t < 4096; t += 256) gs[t] = g1[t];
    __syncthreads();
    int o = threadIdx.x;                      // 0..255
    float acc[8] = {};
    for (int i4 = 0; i4 < 128; ++i4) {
        float w0 = w[(size_t)(i4 * 4 + 0) * 256 + o];
        float w1v = w[(size_t)(i4 * 4 + 1) * 256 + o];
        float w2v = w[(size_t)(i4 * 4 + 2) * 256 + o];
        float w3v = w[(size_t)(i4 * 4 + 3) * 256 + o];
#pragma unroll
        for (int bb = 0; bb < 8; ++bb) {
            float4 f = *(const float4*)&gs[bb * 512 + i4 * 4];
            acc[bb] = fmaf(f.x, w0, fmaf(f.y, w1v, fmaf(f.z, w2v, fmaf(f.w, w3v, acc[bb]))));
        }
    }
    float bo = bias[o];
#pragma unroll
    for (int bb = 0; bb < 8; ++bb) g2[bb * 256 + o] = fmaxf(acc[bb] + bo, 0.f);
}

__global__ void k_fc3sm(const float* __restrict__ g2, const float* __restrict__ w,
                        const float* __restrict__ bias, float* __restrict__ out)
{
    int t = threadIdx.x;      // 128 = 8 batches x 16 lanes
    int b = t >> 4, l = t & 15;
    float lg = -F_INF;
    if (l < 10) {
        float a = bias[l];
        for (int i = 0; i < 256; ++i) a = fmaf(g2[b * 256 + i], w[i * 10 + l], a);
        lg = a;
    }
    float m = lg;
    m = fmaxf(m, __shfl_xor(m, 1, 16));
    m = fmaxf(m, __shfl_xor(m, 2, 16));
    m = fmaxf(m, __shfl_xor(m, 4, 16));
    m = fmaxf(m, __shfl_xor(m, 8, 16));
    float e = (l < 10) ? expf(lg - m) : 0.f;
    float s = e;
    s += __shfl_xor(s, 1, 16);
    s += __shfl_xor(s, 2, 16);
    s += __shfl_xor(s, 4, 16);
    s += __shfl_xor(s, 8, 16);
    if (l < 10) out[b * 10 + l] = (lg - m) - logf(s);
}

// ---------------------------------------------------------------------------
extern "C" void kernel_launch(void* const* d_in, const int* in_sizes, int n_in,
                              void* d_out, int out_size, void* d_ws, size_t ws_size,
                              hipStream_t stream)
{
    (void)in_sizes; (void)n_in; (void)out_size; (void)ws_size;
    const float* data  = (const float*)d_in[0];
    const float* c1w1  = (const float*)d_in[1];
    const float* c1b1  = (const float*)d_in[2];
    const float* c1w2  = (const float*)d_in[3];
    const float* c1b2  = (const float*)d_in[4];
    const float* c1w3  = (const float*)d_in[5];
    const float* c1b3  = (const float*)d_in[6];
    const float* c2w1  = (const float*)d_in[7];
    const float* c2b1  = (const float*)d_in[8];
    const float* lin1w = (const float*)d_in[9];
    const float* lin1b = (const float*)d_in[10];
    const float* mw1   = (const float*)d_in[11];
    const float* mb1   = (const float*)d_in[12];
    const float* mw2   = (const float*)d_in[13];
    const float* mb2   = (const float*)d_in[14];
    const float* mw3   = (const float*)d_in[15];
    const float* mb3   = (const float*)d_in[16];
    float* ws  = (float*)d_ws;
    int*   wsi = (int*)d_ws;
    float* out = (float*)d_out;

    const size_t OFF_IDX1 = 0;          // 655360 i
    const size_t OFF_IDX2 = 0;          // 655360 i (IDX1 dead by then)
    const size_t OFF_X1   = 655360;     // 2097152 f
    const size_t OFF_D2   = 2752512;    // 32768 f
    const size_t OFF_PM   = 2785280;    // 2097152 f
    const size_t OFF_Q    = 4882432;    // 2097152 f
    const size_t OFF_PD   = 2785280;    // 5242880 f   (knn phases)
    const size_t OFF_PI   = 8028160;    // 5242880 i
    const size_t OFF_T    = 2785280;    // 4194304 f
    const size_t OFF_V    = 6979584;    // 4194304 f
    const size_t OFF_X2   = 11173888;   // 4194304 f
    const size_t OFF_PART = 15368192;   // 1048576 f
    const size_t OFF_POOL = 16416768;   // 8192 f
    const size_t OFF_G1   = 16424960;   // 4096 f
    const size_t OFF_G2   = 16429056;   // 2048 f
    // interleaved bf16x3 plane xi[32768][192]: 6291456 ushorts = 3145728
    // float-slots at [13271040, 16416768) — former X2-tail + PART, dead
    // during the knn64 phase. Disjoint from live X1/D2/PD/PI.
    const size_t OFF_XI   = 13271040;

    k_knn2d<<<1024, 256, 0, stream>>>(data, ws + OFF_PD, wsi + OFF_PI);
    k_merge8<<<512, 64, 0, stream>>>(ws + OFF_PD, wsi + OFF_PI, wsi + OFF_IDX1);
    k_prep1<<<8192, 256, 0, stream>>>(data, c1w1, c1b1, ws + OFF_PM, ws + OFF_Q);
    k_edge1<<<2731, 256, 0, stream>>>(ws + OFF_PM, ws + OFF_Q, wsi + OFF_IDX1,
                                      c1w2, c1b2, c1w3, c1b3, ws + OFF_X1, ws + OFF_D2);
    k_split<<<2048, 256, 0, stream>>>(ws + OFF_X1, (unsigned short*)(ws + OFF_XI));
    k_knn64<<<1024, 256, 0, stream>>>((const unsigned short*)(ws + OFF_XI),
                                      ws + OFF_D2, ws + OFF_PD, wsi + OFF_PI);
    k_merge8<<<512, 64, 0, stream>>>(ws + OFF_PD, wsi + OFF_PI, wsi + OFF_IDX2);
    k_prep2<<<4096, 128, 0, stream>>>(ws + OFF_X1, c2w1, c2b1, ws + OFF_T, ws + OFF_V);
    k_edge2<<<4096, 256, 0, stream>>>(ws + OFF_T, ws + OFF_V, wsi + OFF_IDX2, ws + OFF_X2);
    k_lin1max<<<1024, 256, 0, stream>>>(ws + OFF_X1, ws + OFF_X2, lin1w, lin1b, ws + OFF_PART);
    k_red<<<32, 256, 0, stream>>>(ws + OFF_PART, ws + OFF_POOL);
    k_fc1<<<2, 256, 0, stream>>>(ws + OFF_POOL, mw1, mb1, ws + OFF_G1);
    k_fc2<<<1, 256, 0, stream>>>(ws + OFF_G1, mw2, mb2, ws + OFF_G2);
    k_fc3sm<<<1, 128, 0, stream>>>(ws + OFF_G2, mw3, mb3, out);
}